// Round 19
// baseline (154.626 us; speedup 1.0000x reference)
//
#include <hip/hip_runtime.h>
#include <hip/hip_bf16.h>
#include <math.h>

#define T_TOK 4096
#define DIM   1024
#define HDIM  256
#define N_SH  2
#define N_RT  32
#define N_E   34
#define TOPK  4
#define TB    128
#define MAXPB 200
#define NSLOT 6
#define OSW   34          // ostage row stride (32 cols + 2 pad)

typedef short bf16x8 __attribute__((ext_vector_type(8)));
typedef float f32x4  __attribute__((ext_vector_type(4)));
typedef unsigned short u16x8 __attribute__((ext_vector_type(8)));

__device__ __forceinline__ ushort f2b(float v) {
    __hip_bfloat16 h = __float2bfloat16(v);
    return *reinterpret_cast<const ushort*>(&h);
}
__device__ __forceinline__ float b2f(ushort u) {
    unsigned int x = ((unsigned int)u) << 16;
    return __uint_as_float(x);
}
__device__ __forceinline__ float gelu_tanh(float x) {
    float z = 0.7978845608028654f * (x + 0.044715f * x * x * x);
    float e = __expf(2.0f * z);
    float t = 1.0f - 2.0f / (e + 1.0f);
    return 0.5f * x * (1.0f + t);
}

// async global->LDS, 16B per lane; LDS dst wave-uniform base (+lane*16 by HW)
__device__ __forceinline__ void gload_lds16(const ushort* g, ushort* l) {
    __builtin_amdgcn_global_load_lds(
        (const __attribute__((address_space(1))) void*)g,
        (__attribute__((address_space(3))) void*)l,
        16, 0, 0);
}

// ---- pack weights v2: coalesced LDS-transpose (r16-verified) ----
template<int K, int N>
__global__ __launch_bounds__(256) void pack_weights(
    const float* __restrict__ srcS, const float* __restrict__ srcR,
    ushort* __restrict__ dst)
{
    const int e = blockIdx.y;
    const float* src = (e < N_SH) ? (srcS + (size_t)e * K * N)
                                  : (srcR + (size_t)(e - N_SH) * K * N);
    const int kt  = K / 32;
    const int k32 = blockIdx.x % kt;
    const int nc  = blockIdx.x / kt;
    const int tid = threadIdx.x;

    __shared__ ushort ls[32][137];

    #pragma unroll
    for (int it = 0; it < 4; ++it) {
        const int row = it * 8 + (tid >> 5);
        const int c4  = tid & 31;
        const float4 v = *(const float4*)(src + (size_t)(k32 * 32 + row) * N
                                          + nc * 128 + c4 * 4);
        ls[row][c4 * 4 + 0] = f2b(v.x);
        ls[row][c4 * 4 + 1] = f2b(v.y);
        ls[row][c4 * 4 + 2] = f2b(v.z);
        ls[row][c4 * 4 + 3] = f2b(v.w);
    }
    __syncthreads();

    #pragma unroll
    for (int it = 0; it < 2; ++it) {
        const int t8   = tid >> 5;
        const int lane = it * 32 + (tid & 31);
        const int l16 = lane & 15, lk = lane >> 4;
        u16x8 o;
        #pragma unroll
        for (int j = 0; j < 8; ++j)
            o[j] = ls[lk * 8 + j][t8 * 16 + l16];
        const size_t tile = (size_t)(nc * 8 + t8) * kt + k32;
        *(u16x8*)(dst + (size_t)e * K * N + tile * 512 + lane * 8) = o;
    }
}

// ---------------- RMSNorm + router, 4 tokens per block ----------------
__global__ __launch_bounds__(256) void rms_router_kernel(
    const float* __restrict__ x, const float* __restrict__ rms_w,
    const float* __restrict__ cent,
    ushort* __restrict__ xnb, float* __restrict__ aff_out,
    int* __restrict__ tk_e, float* __restrict__ sscore)
{
    const int t0  = blockIdx.x * 4;
    const int tid = threadIdx.x;
    const int wid = tid >> 6;
    const int lane = tid & 63;
    const int t = t0 + wid;

    __shared__ float xsh[4][DIM];
    __shared__ float logits[4][N_RT];

    float4 xv[4], wv[4];
    float ss = 0.f;
    #pragma unroll
    for (int q = 0; q < 4; ++q) {
        xv[q] = ((const float4*)(x + (size_t)t * DIM))[lane + 64 * q];
        ss += xv[q].x*xv[q].x + xv[q].y*xv[q].y + xv[q].z*xv[q].z + xv[q].w*xv[q].w;
    }
    #pragma unroll
    for (int o = 32; o > 0; o >>= 1) ss += __shfl_down(ss, o);
    const float rstd = rsqrtf(__shfl(ss, 0) * (1.0f / (float)DIM) + 1e-6f);

    #pragma unroll
    for (int q = 0; q < 4; ++q)
        wv[q] = ((const float4*)rms_w)[lane + 64 * q];

    #pragma unroll
    for (int q = 0; q < 4; ++q) {
        float4 nv;
        nv.x = xv[q].x * rstd * wv[q].x;
        nv.y = xv[q].y * rstd * wv[q].y;
        nv.z = xv[q].z * rstd * wv[q].z;
        nv.w = xv[q].w * rstd * wv[q].w;
        ushort4 xb = make_ushort4(f2b(nv.x), f2b(nv.y), f2b(nv.z), f2b(nv.w));
        ((ushort4*)(xnb + (size_t)t * DIM))[lane + 64 * q] = xb;
        ((float4*)xsh[wid])[lane + 64 * q] = nv;
    }
    __syncthreads();

    #pragma unroll
    for (int ei = 0; ei < 8; ++ei) {
        const int e = wid * 8 + ei;
        const float4* c4 = (const float4*)(cent + (size_t)e * DIM);
        float a0 = 0.f, a1 = 0.f, a2 = 0.f, a3 = 0.f;
        #pragma unroll
        for (int q = 0; q < 4; ++q) {
            const float4 cv = c4[lane + 64 * q];
            const float4 x0 = ((const float4*)xsh[0])[lane + 64 * q];
            const float4 x1 = ((const float4*)xsh[1])[lane + 64 * q];
            const float4 x2 = ((const float4*)xsh[2])[lane + 64 * q];
            const float4 x3 = ((const float4*)xsh[3])[lane + 64 * q];
            a0 += cv.x*x0.x + cv.y*x0.y + cv.z*x0.z + cv.w*x0.w;
            a1 += cv.x*x1.x + cv.y*x1.y + cv.z*x1.z + cv.w*x1.w;
            a2 += cv.x*x2.x + cv.y*x2.y + cv.z*x2.z + cv.w*x2.w;
            a3 += cv.x*x3.x + cv.y*x3.y + cv.z*x3.z + cv.w*x3.w;
        }
        #pragma unroll
        for (int o = 32; o > 0; o >>= 1) {
            a0 += __shfl_down(a0, o);
            a1 += __shfl_down(a1, o);
            a2 += __shfl_down(a2, o);
            a3 += __shfl_down(a3, o);
        }
        if (lane == 0) {
            logits[0][e] = a0; logits[1][e] = a1;
            logits[2][e] = a2; logits[3][e] = a3;
        }
    }
    __syncthreads();

    {
        float v = (lane < N_RT) ? logits[wid][lane] : -INFINITY;
        float m = v;
        #pragma unroll
        for (int o = 32; o > 0; o >>= 1) m = fmaxf(m, __shfl_xor(m, o));
        float p = (lane < N_RT) ? expf(v - m) : 0.f;
        float s = p;
        #pragma unroll
        for (int o = 32; o > 0; o >>= 1) s += __shfl_xor(s, o);
        const float a = p / s;
        if (lane < N_RT) aff_out[(size_t)t * N_RT + lane] = a;
        if (lane < N_SH) sscore[(size_t)t * NSLOT + lane] = 1.f;

        float vv = (lane < N_RT) ? a : -1.f;
        #pragma unroll
        for (int it = 0; it < TOPK; ++it) {
            float mx = vv;
            #pragma unroll
            for (int o = 32; o > 0; o >>= 1) mx = fmaxf(mx, __shfl_xor(mx, o));
            unsigned long long msk = __ballot(vv == mx);
            int sel = __ffsll((long long)msk) - 1;
            sel = (sel < 0) ? 0 : (sel & (N_RT - 1));
            if (lane == 0) {
                tk_e[(size_t)t * TOPK + it] = sel;
                sscore[(size_t)t * NSLOT + 2 + it] = mx;
            }
            if (lane == sel) vv = -1.f;
        }
    }
}

// ---- scatter: block e compacts (token,slot) entries where tk_e == e ----
__global__ __launch_bounds__(64) void scatter_kernel(
    const int* __restrict__ tk_e, int* __restrict__ counts, int* __restrict__ lists)
{
    const int e    = blockIdx.x;
    const int lane = threadIdx.x;
    const unsigned long long lt = (1ull << lane) - 1ull;
    int base = 0;
    int* lst = lists + (size_t)e * T_TOK;
    for (int c = 0; c < T_TOK * TOPK; c += 256) {
        const int4 v = *(const int4*)(tk_e + c + lane * 4);
        const bool p0 = (v.x == e), p1 = (v.y == e), p2 = (v.z == e), p3 = (v.w == e);
        const unsigned long long m0 = __ballot(p0);
        const unsigned long long m1 = __ballot(p1);
        const unsigned long long m2 = __ballot(p2);
        const unsigned long long m3 = __ballot(p3);
        const int c0 = __popcll(m0), c1 = __popcll(m1), c2 = __popcll(m2);
        if (p0) lst[base + __popcll(m0 & lt)] = c + lane * 4 + 0;
        if (p1) lst[base + c0 + __popcll(m1 & lt)] = c + lane * 4 + 1;
        if (p2) lst[base + c0 + c1 + __popcll(m2 & lt)] = c + lane * 4 + 2;
        if (p3) lst[base + c0 + c1 + c2 + __popcll(m3 & lt)] = c + lane * 4 + 3;
        base += c0 + c1 + c2 + __popcll(m3);
    }
    if (lane == 0) counts[e] = base;
}

// ---- residual init (fallback path only): y = bf16(xn) ----
__global__ __launch_bounds__(256) void residual_init(
    const ushort* __restrict__ xnb, float* __restrict__ y)
{
    const int idx = blockIdx.x * 256 + threadIdx.x;
    const ushort4 xr = *(const ushort4*)(xnb + (size_t)idx * 4);
    float4 a;
    a.x = b2f(xr.x); a.y = b2f(xr.y); a.z = b2f(xr.z); a.w = b2f(xr.w);
    ((float4*)y)[idx] = a;
}

// ---------------- fused 2-layer expert MLP ----------------
// Both operands LDS-staged (r18 pattern extended to B):
// Phase 1 (K=1024): wave (mh=w>>2, nq=w&3) tile M64 x N64. Per step:
//   DMA A(k+1) 8KB + B(k+1) 16KB into dbuf; ds_read A,B of step k; 16 MFMA;
//   __syncthreads (vmcnt drain => step-(k+1) buffers complete).
// Phase 2 (K=256): same for B2; A from hlds. 4 jc chunks x 8 k-steps.
template<bool ATOMIC>
__global__ __launch_bounds__(512, 2) void moe_mfma(
    const ushort* __restrict__ xnb,
    const ushort* __restrict__ W1p, const ushort* __restrict__ W2p,
    const float* __restrict__ sb1, const float* __restrict__ sb2,
    const float* __restrict__ rb1, const float* __restrict__ rb2,
    const int* __restrict__ counts, const int* __restrict__ lists,
    const float* __restrict__ sscore,
    ushort* __restrict__ sbuf, float* __restrict__ y)
{
    const int bi  = blockIdx.x;
    const int tid = threadIdx.x;

    __shared__ int    toks[TB];
    __shared__ int    orow[TB];
    __shared__ float  tscs[TB];
    __shared__ ushort hlds[TB * HDIM];          // 64 KB, XOR-swizzled, stride 512B
    __shared__ ushort astage[2 * 4096];         // 16 KB: [buf][128 tok x 32 dims]
    __shared__ ushort bstage[2 * 8192];         // 32 KB: [buf][16 tiles x 512]
    __shared__ ushort ostage[8 * 64 * OSW];     // 34.8 KB per-wave repack

    int e_full;
    const float *b1, *b2;

    if (bi < 64) {                            // shared experts: 32 tiles x 2
        e_full = bi >> 5;
        const int tile = bi & 31;
        if (tid < TB) {
            const int t = tile * TB + tid;
            toks[tid] = t;
            orow[tid] = ATOMIC ? t : t * NSLOT + e_full;
            tscs[tid] = 1.f;
        }
        b1 = sb1 + e_full * HDIM;  b2 = sb2 + e_full * DIM;
    } else {                                  // routed: bucket walk over counts
        const int j = bi - 64;
        const int b = j & 7, pos = j >> 3;
        int e = -1, tile = 0, accum = 0;
        #pragma unroll
        for (int g = 0; g < 4; ++g) {
            const int eg = b + 8 * g;
            const int tg = (counts[eg] + TB - 1) / TB;
            if (e < 0 && pos < accum + tg) { e = eg; tile = pos - accum; }
            accum += tg;
        }
        if (e < 0) return;
        e_full = N_SH + e;
        const int cnt = counts[e];
        if (tid < TB) {
            const int idx = tile * TB + tid;
            if (idx < cnt) {
                const int lv = lists[(size_t)e * T_TOK + idx];
                const int t = (lv >> 2) & (T_TOK - 1);
                toks[tid] = t;
                orow[tid] = ATOMIC ? t : t * NSLOT + 2 + (lv & 3);
                tscs[tid] = ATOMIC ? sscore[(size_t)t * NSLOT + 2 + (lv & 3)] : 0.f;
            } else {
                toks[tid] = 0;
                orow[tid] = ATOMIC ? 0 : T_TOK * NSLOT;   // dummy row
                tscs[tid] = 0.f;
            }
        }
        b1 = rb1 + e * HDIM;  b2 = rb2 + e * DIM;
    }
    __syncthreads();

    const int w = tid >> 6, lane = tid & 63;
    const int l16 = lane & 15, lk = lane >> 4;
    const int mh = w >> 2;          // token half (64 rows)
    const int nq = w & 3;           // N quarter (64 cols)

    const ushort* W1e = W1p + (size_t)e_full * DIM * HDIM;
    const ushort* W2e = W2p + (size_t)e_full * HDIM * DIM;

    // ---- phase 1: C1[128,256] = X @ W1, A+B LDS-staged ----
    {
        // wave w stages: A chunk for tokens w*16..+15, and B tiles q=2w, 2w+1
        const ushort* asrc = xnb + (size_t)toks[w * 16 + (lane >> 2)] * DIM
                             + (lane & 3) * 8;
        gload_lds16(asrc, astage + w * 512);
        #pragma unroll
        for (int s2 = 0; s2 < 2; ++s2) {
            const int q = w * 2 + s2;
            gload_lds16(W1e + (size_t)(q * 32 + 0) * 512 + lane * 8,
                        bstage + q * 512);
        }

        f32x4 acc[4][4];
        #pragma unroll
        for (int mi = 0; mi < 4; ++mi)
            #pragma unroll
            for (int ni = 0; ni < 4; ++ni) acc[mi][ni] = (f32x4){0.f,0.f,0.f,0.f};
        __syncthreads();                      // stage(0) + toks drained

        #pragma unroll 2
        for (int k32 = 0; k32 < 32; ++k32) {
            const int cur = k32 & 1;
            if (k32 < 31) {
                gload_lds16(asrc + (k32 + 1) * 32,
                            astage + (cur ^ 1) * 4096 + w * 512);
                #pragma unroll
                for (int s2 = 0; s2 < 2; ++s2) {
                    const int q = w * 2 + s2;
                    gload_lds16(W1e + (size_t)(q * 32 + k32 + 1) * 512 + lane * 8,
                                bstage + (cur ^ 1) * 8192 + q * 512);
                }
            }
            bf16x8 a[4], bf[4];
            #pragma unroll
            for (int mi = 0; mi < 4; ++mi) {
                const int tloc = mh * 64 + mi * 16 + l16;
                a[mi] = *(const bf16x8*)(astage + cur * 4096 + tloc * 32 + lk * 8);
            }
            #pragma unroll
            for (int ni = 0; ni < 4; ++ni)
                bf[ni] = *(const bf16x8*)(bstage + cur * 8192 + (nq * 4 + ni) * 512 + lane * 8);
            #pragma unroll
            for (int ni = 0; ni < 4; ++ni)
                #pragma unroll
                for (int mi = 0; mi < 4; ++mi)
                    acc[mi][ni] = __builtin_amdgcn_mfma_f32_16x16x32_bf16(a[mi], bf[ni], acc[mi][ni], 0, 0, 0);
            __syncthreads();                  // drains DMA(k+1); buf swap safe
        }

        // stage phase-2 s=0 (jc=0,k32=0) into bstage buf0 (free since k=30)
        #pragma unroll
        for (int s2 = 0; s2 < 2; ++s2) {
            const int q = w * 2 + s2;
            gload_lds16(W2e + (size_t)((0 * 16 + q) * 8 + 0) * 512 + lane * 8,
                        bstage + q * 512);
        }

        // h = bf16(C1 + b1) -> swizzled LDS [128 rows][256 cols]
        #pragma unroll
        for (int ni = 0; ni < 4; ++ni) {
            const int n = nq * 64 + ni * 16 + l16;
            const float bv = b1[n];
            #pragma unroll
            for (int mi = 0; mi < 4; ++mi) {
                #pragma unroll
                for (int r = 0; r < 4; ++r) {
                    const int m = mh * 64 + mi * 16 + lk * 4 + r;
                    const int byte = (m * (HDIM * 2) + n * 2) ^ ((m & 7) << 4);
                    *(ushort*)((char*)hlds + byte) = f2b(acc[mi][ni][r] + bv);
                }
            }
        }
    }
    __syncthreads();                          // h visible + B2(0) staged

    // ---- phase 2: C2[128,1024] = h @ W2, 32 steps, B LDS-staged ----
    {
        f32x4 acc2[4][4];
        #pragma unroll
        for (int mi = 0; mi < 4; ++mi)
            #pragma unroll
            for (int ni = 0; ni < 4; ++ni) acc2[mi][ni] = (f32x4){0.f,0.f,0.f,0.f};

        #pragma unroll 2
        for (int s = 0; s < 32; ++s) {
            const int jc  = s >> 3;
            const int k32 = s & 7;
            const int cur = s & 1;

            if (s < 31) {
                const int s2 = s + 1;
                const int jc2 = s2 >> 3, kk2 = s2 & 7;
                #pragma unroll
                for (int q2 = 0; q2 < 2; ++q2) {
                    const int q = w * 2 + q2;
                    gload_lds16(W2e + (size_t)((jc2 * 16 + q) * 8 + kk2) * 512 + lane * 8,
                                bstage + (cur ^ 1) * 8192 + q * 512);
                }
            }

            bf16x8 a2[4], bf2[4];
            #pragma unroll
            for (int mi = 0; mi < 4; ++mi) {
                const int m = mh * 64 + mi * 16 + l16;
                const int byte = (m * (HDIM * 2) + (k32 * 32 + lk * 8) * 2) ^ ((m & 7) << 4);
                a2[mi] = *(const bf16x8*)((const char*)hlds + byte);
            }
            #pragma unroll
            for (int ni = 0; ni < 4; ++ni)
                bf2[ni] = *(const bf16x8*)(bstage + cur * 8192 + (nq * 4 + ni) * 512 + lane * 8);

            #pragma unroll
            for (int ni = 0; ni < 4; ++ni)
                #pragma unroll
                for (int mi = 0; mi < 4; ++mi)
                    acc2[mi][ni] = __builtin_amdgcn_mfma_f32_16x16x32_bf16(a2[mi], bf2[ni], acc2[mi][ni], 0, 0, 0);

            if (k32 == 7) {
                if (ATOMIC) {
                    #pragma unroll
                    for (int ni = 0; ni < 4; ++ni) {
                        const int n = jc * 256 + nq * 64 + ni * 16 + l16;
                        const float bv = b2[n];
                        #pragma unroll
                        for (int mi = 0; mi < 4; ++mi)
                            #pragma unroll
                            for (int r = 0; r < 4; ++r) {
                                const int m = mi * 16 + lk * 4 + r;
                                const float val = gelu_tanh(acc2[mi][ni][r] + bv) * tscs[mh * 64 + m];
                                atomicAdd(&y[(size_t)orow[mh * 64 + m] * DIM + n], val);
                            }
                    }
                } else {
                    ushort* os = ostage + w * (64 * OSW);
                    #pragma unroll
                    for (int p = 0; p < 2; ++p) {
                        asm volatile("s_waitcnt lgkmcnt(0)" ::: "memory");
                        #pragma unroll
                        for (int q = 0; q < 2; ++q) {
                            const int ni = p * 2 + q;
                            const float bv = b2[jc * 256 + nq * 64 + ni * 16 + l16];
                            #pragma unroll
                            for (int mi = 0; mi < 4; ++mi)
                                #pragma unroll
                                for (int r = 0; r < 4; ++r) {
                                    const int m = mi * 16 + lk * 4 + r;
                                    os[m * OSW + q * 16 + l16] = f2b(acc2[mi][ni][r] + bv);
                                }
                        }
                        asm volatile("s_waitcnt lgkmcnt(0)" ::: "memory");
                        #pragma unroll
                        for (int rr = 0; rr < 4; ++rr) {
                            const int m  = rr * 16 + (lane >> 2);
                            const int nl = (lane & 3) * 8;
                            u16x8 vv = *(const u16x8*)(os + m * OSW + nl);
                            *(u16x8*)(sbuf + (size_t)orow[mh * 64 + m] * DIM
                                      + jc * 256 + nq * 64 + p * 32 + nl) = vv;
                        }
                    }
                }
                #pragma unroll
                for (int mi = 0; mi < 4; ++mi)
                    #pragma unroll
                    for (int ni = 0; ni < 4; ++ni) acc2[mi][ni] = (f32x4){0.f,0.f,0.f,0.f};
            }
            __syncthreads();                  // drains DMA(s+1)
        }
    }
}

// ---------------- gather: y = bf16(xn) + sum_s gelu(slot)*score ----------------
__global__ __launch_bounds__(256) void gather_kernel(
    const ushort* __restrict__ sbuf, const float* __restrict__ sscore,
    const ushort* __restrict__ xnb, float* __restrict__ y)
{
    const int idx = blockIdx.x * 256 + threadIdx.x;
    const int t = idx >> 8;
    const int d = (idx & 255) * 4;
    const ushort4 xr = *(const ushort4*)(xnb + (size_t)t * DIM + d);
    float4 a;
    a.x = b2f(xr.x); a.y = b2f(xr.y); a.z = b2f(xr.z); a.w = b2f(xr.w);
    #pragma unroll
    for (int s = 0; s < NSLOT; ++s) {
        const float sc = sscore[(size_t)t * NSLOT + s];
        const ushort4 u = *(const ushort4*)(sbuf + ((size_t)t * NSLOT + s) * DIM + d);
        a.x += gelu_tanh(b2f(u.x)) * sc;
        a.y += gelu_tanh(b2f(u.y)) * sc;
        a.z += gelu_tanh(b2f(u.z)) * sc;
        a.w += gelu_tanh(b2f(u.w)) * sc;
    }
    ((float4*)y)[idx] = a;
}

extern "C" void kernel_launch(void* const* d_in, const int* in_sizes, int n_in,
                              void* d_out, int out_size, void* d_ws, size_t ws_size,
                              hipStream_t stream) {
    const float* x      = (const float*)d_in[0];
    const float* rms_w  = (const float*)d_in[1];
    const float* cent   = (const float*)d_in[2];
    const float* sW1    = (const float*)d_in[3];
    const float* sb1    = (const float*)d_in[4];
    const float* sW2    = (const float*)d_in[5];
    const float* sb2    = (const float*)d_in[6];
    const float* rW1    = (const float*)d_in[7];
    const float* rb1    = (const float*)d_in[8];
    const float* rW2    = (const float*)d_in[9];
    const float* rb2    = (const float*)d_in[10];

    float* y_out   = (float*)d_out;
    float* aff_out = (float*)d_out + (size_t)T_TOK * DIM;

    char* p = (char*)d_ws;
    size_t off = 0;
    auto take = [&](size_t b) {
        char* r = p + off;
        off += (b + 255) & ~(size_t)255;
        return r;
    };
    ushort* xnb    = (ushort*)take((size_t)T_TOK * DIM * 2);
    ushort* W1p    = (ushort*)take((size_t)N_E * DIM * HDIM * 2);
    ushort* W2p    = (ushort*)take((size_t)N_E * HDIM * DIM * 2);
    int*    counts = (int*)take(N_RT * sizeof(int));
    int*    lists  = (int*)take((size_t)N_RT * T_TOK * 4);
    float*  sscore = (float*)take((size_t)T_TOK * NSLOT * 4);
    int*    tk_e   = (int*)take((size_t)T_TOK * TOPK * 4);
    ushort* sbuf   = (ushort*)take(((size_t)T_TOK * NSLOT + TB) * DIM * 2);
    const bool slot_ok = (off <= ws_size);

    pack_weights<DIM, HDIM><<<dim3(64, N_E), dim3(256), 0, stream>>>(sW1, rW1, W1p);
    pack_weights<HDIM, DIM><<<dim3(64, N_E), dim3(256), 0, stream>>>(sW2, rW2, W2p);

    rms_router_kernel<<<dim3(T_TOK / 4), dim3(256), 0, stream>>>(
        x, rms_w, cent, xnb, aff_out, tk_e, sscore);

    scatter_kernel<<<dim3(N_RT), dim3(64), 0, stream>>>(tk_e, counts, lists);

    const int grid = 64 + 8 * MAXPB;
    if (slot_ok) {
        moe_mfma<false><<<dim3(grid), dim3(512), 0, stream>>>(
            xnb, W1p, W2p, sb1, sb2, rb1, rb2, counts, lists,
            sscore, sbuf, y_out);
        gather_kernel<<<dim3((T_TOK * DIM / 4) / 256), dim3(256), 0, stream>>>(
            sbuf, sscore, xnb, y_out);
    } else {
        residual_init<<<dim3((T_TOK * DIM / 4) / 256), dim3(256), 0, stream>>>(
            xnb, y_out);
        moe_mfma<true><<<dim3(grid), dim3(512), 0, stream>>>(
            xnb, W1p, W2p, sb1, sb2, rb1, rb2, counts, lists,
            sscore, sbuf, y_out);
    }
}

// Round 20
// 139.974 us; speedup vs baseline: 1.1047x; 1.1047x over previous
//
#include <hip/hip_runtime.h>
#include <hip/hip_bf16.h>
#include <math.h>

#define T_TOK 4096
#define DIM   1024
#define HDIM  256
#define N_SH  2
#define N_RT  32
#define N_E   34
#define TOPK  4
#define TB    128
#define MAXPB 200
#define NSLOT 6
#define OSW   34          // ostage row stride (32 cols + 2 pad)

typedef short bf16x8 __attribute__((ext_vector_type(8)));
typedef float f32x4  __attribute__((ext_vector_type(4)));
typedef unsigned short u16x8 __attribute__((ext_vector_type(8)));

__device__ __forceinline__ ushort f2b(float v) {
    __hip_bfloat16 h = __float2bfloat16(v);
    return *reinterpret_cast<const ushort*>(&h);
}
__device__ __forceinline__ float b2f(ushort u) {
    unsigned int x = ((unsigned int)u) << 16;
    return __uint_as_float(x);
}
__device__ __forceinline__ float gelu_tanh(float x) {
    float z = 0.7978845608028654f * (x + 0.044715f * x * x * x);
    float e = __expf(2.0f * z);
    float t = 1.0f - 2.0f / (e + 1.0f);
    return 0.5f * x * (1.0f + t);
}

// async global->LDS, 16B per lane; LDS dst wave-uniform base (+lane*16 by HW)
__device__ __forceinline__ void gload_lds16(const ushort* g, ushort* l) {
    __builtin_amdgcn_global_load_lds(
        (const __attribute__((address_space(1))) void*)g,
        (__attribute__((address_space(3))) void*)l,
        16, 0, 0);
}

#define SBAR() __builtin_amdgcn_sched_barrier(0)

// ---- pack weights v2: coalesced LDS-transpose (r16-verified) ----
template<int K, int N>
__global__ __launch_bounds__(256) void pack_weights(
    const float* __restrict__ srcS, const float* __restrict__ srcR,
    ushort* __restrict__ dst)
{
    const int e = blockIdx.y;
    const float* src = (e < N_SH) ? (srcS + (size_t)e * K * N)
                                  : (srcR + (size_t)(e - N_SH) * K * N);
    const int kt  = K / 32;
    const int k32 = blockIdx.x % kt;
    const int nc  = blockIdx.x / kt;
    const int tid = threadIdx.x;

    __shared__ ushort ls[32][137];

    #pragma unroll
    for (int it = 0; it < 4; ++it) {
        const int row = it * 8 + (tid >> 5);
        const int c4  = tid & 31;
        const float4 v = *(const float4*)(src + (size_t)(k32 * 32 + row) * N
                                          + nc * 128 + c4 * 4);
        ls[row][c4 * 4 + 0] = f2b(v.x);
        ls[row][c4 * 4 + 1] = f2b(v.y);
        ls[row][c4 * 4 + 2] = f2b(v.z);
        ls[row][c4 * 4 + 3] = f2b(v.w);
    }
    __syncthreads();

    #pragma unroll
    for (int it = 0; it < 2; ++it) {
        const int t8   = tid >> 5;
        const int lane = it * 32 + (tid & 31);
        const int l16 = lane & 15, lk = lane >> 4;
        u16x8 o;
        #pragma unroll
        for (int j = 0; j < 8; ++j)
            o[j] = ls[lk * 8 + j][t8 * 16 + l16];
        const size_t tile = (size_t)(nc * 8 + t8) * kt + k32;
        *(u16x8*)(dst + (size_t)e * K * N + tile * 512 + lane * 8) = o;
    }
}

// ---------------- RMSNorm + router, 4 tokens per block ----------------
__global__ __launch_bounds__(256) void rms_router_kernel(
    const float* __restrict__ x, const float* __restrict__ rms_w,
    const float* __restrict__ cent,
    ushort* __restrict__ xnb, float* __restrict__ aff_out,
    int* __restrict__ tk_e, float* __restrict__ sscore)
{
    const int t0  = blockIdx.x * 4;
    const int tid = threadIdx.x;
    const int wid = tid >> 6;
    const int lane = tid & 63;
    const int t = t0 + wid;

    __shared__ float xsh[4][DIM];
    __shared__ float logits[4][N_RT];

    float4 xv[4], wv[4];
    float ss = 0.f;
    #pragma unroll
    for (int q = 0; q < 4; ++q) {
        xv[q] = ((const float4*)(x + (size_t)t * DIM))[lane + 64 * q];
        ss += xv[q].x*xv[q].x + xv[q].y*xv[q].y + xv[q].z*xv[q].z + xv[q].w*xv[q].w;
    }
    #pragma unroll
    for (int o = 32; o > 0; o >>= 1) ss += __shfl_down(ss, o);
    const float rstd = rsqrtf(__shfl(ss, 0) * (1.0f / (float)DIM) + 1e-6f);

    #pragma unroll
    for (int q = 0; q < 4; ++q)
        wv[q] = ((const float4*)rms_w)[lane + 64 * q];

    #pragma unroll
    for (int q = 0; q < 4; ++q) {
        float4 nv;
        nv.x = xv[q].x * rstd * wv[q].x;
        nv.y = xv[q].y * rstd * wv[q].y;
        nv.z = xv[q].z * rstd * wv[q].z;
        nv.w = xv[q].w * rstd * wv[q].w;
        ushort4 xb = make_ushort4(f2b(nv.x), f2b(nv.y), f2b(nv.z), f2b(nv.w));
        ((ushort4*)(xnb + (size_t)t * DIM))[lane + 64 * q] = xb;
        ((float4*)xsh[wid])[lane + 64 * q] = nv;
    }
    __syncthreads();

    #pragma unroll
    for (int ei = 0; ei < 8; ++ei) {
        const int e = wid * 8 + ei;
        const float4* c4 = (const float4*)(cent + (size_t)e * DIM);
        float a0 = 0.f, a1 = 0.f, a2 = 0.f, a3 = 0.f;
        #pragma unroll
        for (int q = 0; q < 4; ++q) {
            const float4 cv = c4[lane + 64 * q];
            const float4 x0 = ((const float4*)xsh[0])[lane + 64 * q];
            const float4 x1 = ((const float4*)xsh[1])[lane + 64 * q];
            const float4 x2 = ((const float4*)xsh[2])[lane + 64 * q];
            const float4 x3 = ((const float4*)xsh[3])[lane + 64 * q];
            a0 += cv.x*x0.x + cv.y*x0.y + cv.z*x0.z + cv.w*x0.w;
            a1 += cv.x*x1.x + cv.y*x1.y + cv.z*x1.z + cv.w*x1.w;
            a2 += cv.x*x2.x + cv.y*x2.y + cv.z*x2.z + cv.w*x2.w;
            a3 += cv.x*x3.x + cv.y*x3.y + cv.z*x3.z + cv.w*x3.w;
        }
        #pragma unroll
        for (int o = 32; o > 0; o >>= 1) {
            a0 += __shfl_down(a0, o);
            a1 += __shfl_down(a1, o);
            a2 += __shfl_down(a2, o);
            a3 += __shfl_down(a3, o);
        }
        if (lane == 0) {
            logits[0][e] = a0; logits[1][e] = a1;
            logits[2][e] = a2; logits[3][e] = a3;
        }
    }
    __syncthreads();

    {
        float v = (lane < N_RT) ? logits[wid][lane] : -INFINITY;
        float m = v;
        #pragma unroll
        for (int o = 32; o > 0; o >>= 1) m = fmaxf(m, __shfl_xor(m, o));
        float p = (lane < N_RT) ? expf(v - m) : 0.f;
        float s = p;
        #pragma unroll
        for (int o = 32; o > 0; o >>= 1) s += __shfl_xor(s, o);
        const float a = p / s;
        if (lane < N_RT) aff_out[(size_t)t * N_RT + lane] = a;
        if (lane < N_SH) sscore[(size_t)t * NSLOT + lane] = 1.f;

        float vv = (lane < N_RT) ? a : -1.f;
        #pragma unroll
        for (int it = 0; it < TOPK; ++it) {
            float mx = vv;
            #pragma unroll
            for (int o = 32; o > 0; o >>= 1) mx = fmaxf(mx, __shfl_xor(mx, o));
            unsigned long long msk = __ballot(vv == mx);
            int sel = __ffsll((long long)msk) - 1;
            sel = (sel < 0) ? 0 : (sel & (N_RT - 1));
            if (lane == 0) {
                tk_e[(size_t)t * TOPK + it] = sel;
                sscore[(size_t)t * NSLOT + 2 + it] = mx;
            }
            if (lane == sel) vv = -1.f;
        }
    }
}

// ---- scatter: block e compacts (token,slot) entries where tk_e == e ----
__global__ __launch_bounds__(64) void scatter_kernel(
    const int* __restrict__ tk_e, int* __restrict__ counts, int* __restrict__ lists)
{
    const int e    = blockIdx.x;
    const int lane = threadIdx.x;
    const unsigned long long lt = (1ull << lane) - 1ull;
    int base = 0;
    int* lst = lists + (size_t)e * T_TOK;
    for (int c = 0; c < T_TOK * TOPK; c += 256) {
        const int4 v = *(const int4*)(tk_e + c + lane * 4);
        const bool p0 = (v.x == e), p1 = (v.y == e), p2 = (v.z == e), p3 = (v.w == e);
        const unsigned long long m0 = __ballot(p0);
        const unsigned long long m1 = __ballot(p1);
        const unsigned long long m2 = __ballot(p2);
        const unsigned long long m3 = __ballot(p3);
        const int c0 = __popcll(m0), c1 = __popcll(m1), c2 = __popcll(m2);
        if (p0) lst[base + __popcll(m0 & lt)] = c + lane * 4 + 0;
        if (p1) lst[base + c0 + __popcll(m1 & lt)] = c + lane * 4 + 1;
        if (p2) lst[base + c0 + c1 + __popcll(m2 & lt)] = c + lane * 4 + 2;
        if (p3) lst[base + c0 + c1 + c2 + __popcll(m3 & lt)] = c + lane * 4 + 3;
        base += c0 + c1 + c2 + __popcll(m3);
    }
    if (lane == 0) counts[e] = base;
}

// ---- residual init (fallback path only): y = bf16(xn) ----
__global__ __launch_bounds__(256) void residual_init(
    const ushort* __restrict__ xnb, float* __restrict__ y)
{
    const int idx = blockIdx.x * 256 + threadIdx.x;
    const ushort4 xr = *(const ushort4*)(xnb + (size_t)idx * 4);
    float4 a;
    a.x = b2f(xr.x); a.y = b2f(xr.y); a.z = b2f(xr.z); a.w = b2f(xr.w);
    ((float4*)y)[idx] = a;
}

// ---------------- fused 2-layer expert MLP ----------------
// Phase 1 (K=1024): wave (mh,nq) tile M64xN64; A staged via global_load_lds,
//   TRIPLE-buffered, counted vmcnt (T4): DMA(k+2) issued at step k; barrier
//   waits vmcnt(5) = retire DMA(k+1), keep {B(k+1)x4, DMA(k+2)} in flight.
//   lgkmcnt(0)+sched_barrier before each DMA preserves the read->overwrite
//   anti-dependence (r8 lesson); raw s_barrier (no vmcnt(0) drain).
// Phase 2 (K=256): r18-exact (barrier-free, reg-prefetch B, A from hlds).
template<bool ATOMIC>
__global__ __launch_bounds__(512, 2) void moe_mfma(
    const ushort* __restrict__ xnb,
    const ushort* __restrict__ W1p, const ushort* __restrict__ W2p,
    const float* __restrict__ sb1, const float* __restrict__ sb2,
    const float* __restrict__ rb1, const float* __restrict__ rb2,
    const int* __restrict__ counts, const int* __restrict__ lists,
    const float* __restrict__ sscore,
    ushort* __restrict__ sbuf, float* __restrict__ y)
{
    const int bi  = blockIdx.x;
    const int tid = threadIdx.x;

    __shared__ int    toks[TB];
    __shared__ int    orow[TB];
    __shared__ float  tscs[TB];
    __shared__ ushort hlds[TB * HDIM];          // 64 KB, XOR-swizzled, stride 512B
    __shared__ ushort astage[3 * 4096];         // 24 KB: [3 bufs][128 tok x 32 dims]
    __shared__ ushort ostage[8 * 64 * OSW];     // 34.8 KB per-wave repack

    int e_full;
    const float *b1, *b2;

    if (bi < 64) {                            // shared experts: 32 tiles x 2
        e_full = bi >> 5;
        const int tile = bi & 31;
        if (tid < TB) {
            const int t = tile * TB + tid;
            toks[tid] = t;
            orow[tid] = ATOMIC ? t : t * NSLOT + e_full;
            tscs[tid] = 1.f;
        }
        b1 = sb1 + e_full * HDIM;  b2 = sb2 + e_full * DIM;
    } else {                                  // routed: bucket walk over counts
        const int j = bi - 64;
        const int b = j & 7, pos = j >> 3;
        int e = -1, tile = 0, accum = 0;
        #pragma unroll
        for (int g = 0; g < 4; ++g) {
            const int eg = b + 8 * g;
            const int tg = (counts[eg] + TB - 1) / TB;
            if (e < 0 && pos < accum + tg) { e = eg; tile = pos - accum; }
            accum += tg;
        }
        if (e < 0) return;
        e_full = N_SH + e;
        const int cnt = counts[e];
        if (tid < TB) {
            const int idx = tile * TB + tid;
            if (idx < cnt) {
                const int lv = lists[(size_t)e * T_TOK + idx];
                const int t = (lv >> 2) & (T_TOK - 1);
                toks[tid] = t;
                orow[tid] = ATOMIC ? t : t * NSLOT + 2 + (lv & 3);
                tscs[tid] = ATOMIC ? sscore[(size_t)t * NSLOT + 2 + (lv & 3)] : 0.f;
            } else {
                toks[tid] = 0;
                orow[tid] = ATOMIC ? 0 : T_TOK * NSLOT;   // dummy row
                tscs[tid] = 0.f;
            }
        }
        b1 = rb1 + e * HDIM;  b2 = rb2 + e * DIM;
    }
    __syncthreads();

    const int w = tid >> 6, lane = tid & 63;
    const int l16 = lane & 15, lk = lane >> 4;
    const int mh = w >> 2;          // token half (64 rows)
    const int nq = w & 3;           // N quarter (64 cols)

    const ushort* W1e = W1p + (size_t)e_full * DIM * HDIM;
    const ushort* W2e = W2p + (size_t)e_full * HDIM * DIM;

    // ---- phase 1: C1[128,256] = X @ W1, A triple-buffered LDS, counted vmcnt ----
    {
        const ushort* asrc = xnb + (size_t)toks[w * 16 + (lane >> 2)] * DIM
                             + (lane & 3) * 8;
        // prologue: DMA(0)->buf0, DMA(1)->buf1 (pinned oldest in VMEM queue)
        SBAR();
        gload_lds16(asrc,      astage + 0 * 4096 + w * 512);
        gload_lds16(asrc + 32, astage + 1 * 4096 + w * 512);
        SBAR();

        const ushort* bbase[4];
        #pragma unroll
        for (int ni = 0; ni < 4; ++ni)
            bbase[ni] = W1e + (size_t)((nq * 4 + ni) * 32) * 512 + lane * 8;

        f32x4 acc[4][4];
        #pragma unroll
        for (int mi = 0; mi < 4; ++mi)
            #pragma unroll
            for (int ni = 0; ni < 4; ++ni) acc[mi][ni] = (f32x4){0.f,0.f,0.f,0.f};

        bf16x8 bc[4];
        #pragma unroll
        for (int ni = 0; ni < 4; ++ni) bc[ni] = *(const bf16x8*)bbase[ni];

        // retire DMA(0); {DMA(1), B(0)x4} stay in flight
        asm volatile("s_waitcnt vmcnt(5)" ::: "memory");
        __builtin_amdgcn_s_barrier();
        SBAR();

        #pragma unroll 2
        for (int k32 = 0; k32 < 32; ++k32) {
            const int cur = k32 % 3;
            bf16x8 a[4], bn[4];
            #pragma unroll
            for (int mi = 0; mi < 4; ++mi) {
                const int tloc = mh * 64 + mi * 16 + l16;
                a[mi] = *(const bf16x8*)(astage + cur * 4096 + tloc * 32 + lk * 8);
            }
            if (k32 < 31) {
                #pragma unroll
                for (int ni = 0; ni < 4; ++ni)
                    bn[ni] = *(const bf16x8*)(bbase[ni] + (size_t)(k32 + 1) * 512);
            }
            #pragma unroll
            for (int ni = 0; ni < 4; ++ni)
                #pragma unroll
                for (int mi = 0; mi < 4; ++mi)
                    acc[mi][ni] = __builtin_amdgcn_mfma_f32_16x16x32_bf16(a[mi], bc[ni], acc[mi][ni], 0, 0, 0);
            if (k32 < 31) {
                #pragma unroll
                for (int ni = 0; ni < 4; ++ni) bc[ni] = bn[ni];
            }

            if (k32 < 30) {
                // pinned DMA region: overwrite buf[(k+2)%3] (= buf[(k-1)%3],
                // whose reads all waves drained before barrier(k-1))
                asm volatile("s_waitcnt lgkmcnt(0)" ::: "memory");
                SBAR();
                gload_lds16(asrc + (k32 + 2) * 32,
                            astage + ((k32 + 2) % 3) * 4096 + w * 512);
                SBAR();
                // retire DMA(k+1); keep {B(k+1)x4, DMA(k+2)} in flight
                asm volatile("s_waitcnt vmcnt(5)" ::: "memory");
                __builtin_amdgcn_s_barrier();
                SBAR();
            } else if (k32 == 30) {
                // no new DMA; retire DMA(31), keep B(31)x4 in flight
                asm volatile("s_waitcnt vmcnt(4)" ::: "memory");
                __builtin_amdgcn_s_barrier();
                SBAR();
            }
            // k32 == 31: fall through to h epilogue (full __syncthreads below)
        }

        // h = bf16(C1 + b1) -> swizzled LDS [128 rows][256 cols]
        #pragma unroll
        for (int ni = 0; ni < 4; ++ni) {
            const int n = nq * 64 + ni * 16 + l16;
            const float bv = b1[n];
            #pragma unroll
            for (int mi = 0; mi < 4; ++mi) {
                #pragma unroll
                for (int r = 0; r < 4; ++r) {
                    const int m = mh * 64 + mi * 16 + lk * 4 + r;
                    const int byte = (m * (HDIM * 2) + n * 2) ^ ((m & 7) << 4);
                    *(ushort*)((char*)hlds + byte) = f2b(acc[mi][ni][r] + bv);
                }
            }
        }
    }
    __syncthreads();

    // ---- phase 2: C2[128,1024] = h @ W2, 4 jc chunks x 8 k-steps (r18-exact) ----
    {
        for (int jc = 0; jc < 4; ++jc) {
            f32x4 acc2[4][4];
            #pragma unroll
            for (int mi = 0; mi < 4; ++mi)
                #pragma unroll
                for (int ni = 0; ni < 4; ++ni) acc2[mi][ni] = (f32x4){0.f,0.f,0.f,0.f};

            const ushort* b2base[4];
            #pragma unroll
            for (int ni = 0; ni < 4; ++ni)
                b2base[ni] = W2e + (size_t)((jc * 16 + nq * 4 + ni) * 8) * 512 + lane * 8;

            bf16x8 bc2[4];
            #pragma unroll
            for (int ni = 0; ni < 4; ++ni) bc2[ni] = *(const bf16x8*)b2base[ni];

            #pragma unroll
            for (int k32 = 0; k32 < 8; ++k32) {
                bf16x8 a2[4];
                #pragma unroll
                for (int mi = 0; mi < 4; ++mi) {
                    const int m = mh * 64 + mi * 16 + l16;
                    const int byte = (m * (HDIM * 2) + (k32 * 32 + lk * 8) * 2) ^ ((m & 7) << 4);
                    a2[mi] = *(const bf16x8*)((const char*)hlds + byte);
                }
                bf16x8 bn2[4];
                if (k32 < 7) {
                    #pragma unroll
                    for (int ni = 0; ni < 4; ++ni)
                        bn2[ni] = *(const bf16x8*)(b2base[ni] + (size_t)(k32 + 1) * 512);
                }
                #pragma unroll
                for (int ni = 0; ni < 4; ++ni)
                    #pragma unroll
                    for (int mi = 0; mi < 4; ++mi)
                        acc2[mi][ni] = __builtin_amdgcn_mfma_f32_16x16x32_bf16(a2[mi], bc2[ni], acc2[mi][ni], 0, 0, 0);
                if (k32 < 7) {
                    #pragma unroll
                    for (int ni = 0; ni < 4; ++ni) bc2[ni] = bn2[ni];
                }
            }

            if (ATOMIC) {
                #pragma unroll
                for (int ni = 0; ni < 4; ++ni) {
                    const int n = jc * 256 + nq * 64 + ni * 16 + l16;
                    const float bv = b2[n];
                    #pragma unroll
                    for (int mi = 0; mi < 4; ++mi)
                        #pragma unroll
                        for (int r = 0; r < 4; ++r) {
                            const int m = mi * 16 + lk * 4 + r;
                            const float val = gelu_tanh(acc2[mi][ni][r] + bv) * tscs[mh * 64 + m];
                            atomicAdd(&y[(size_t)orow[mh * 64 + m] * DIM + n], val);
                        }
                }
            } else {
                ushort* os = ostage + w * (64 * OSW);
                #pragma unroll
                for (int p = 0; p < 2; ++p) {
                    asm volatile("s_waitcnt lgkmcnt(0)" ::: "memory");
                    #pragma unroll
                    for (int q = 0; q < 2; ++q) {
                        const int ni = p * 2 + q;
                        const float bv = b2[jc * 256 + nq * 64 + ni * 16 + l16];
                        #pragma unroll
                        for (int mi = 0; mi < 4; ++mi)
                            #pragma unroll
                            for (int r = 0; r < 4; ++r) {
                                const int m = mi * 16 + lk * 4 + r;
                                os[m * OSW + q * 16 + l16] = f2b(acc2[mi][ni][r] + bv);
                            }
                    }
                    asm volatile("s_waitcnt lgkmcnt(0)" ::: "memory");
                    #pragma unroll
                    for (int rr = 0; rr < 4; ++rr) {
                        const int m  = rr * 16 + (lane >> 2);
                        const int nl = (lane & 3) * 8;
                        u16x8 vv = *(const u16x8*)(os + m * OSW + nl);
                        *(u16x8*)(sbuf + (size_t)orow[mh * 64 + m] * DIM
                                  + jc * 256 + nq * 64 + p * 32 + nl) = vv;
                    }
                }
            }
        }
    }
}

// ---------------- gather: y = bf16(xn) + sum_s gelu(slot)*score ----------------
__global__ __launch_bounds__(256) void gather_kernel(
    const ushort* __restrict__ sbuf, const float* __restrict__ sscore,
    const ushort* __restrict__ xnb, float* __restrict__ y)
{
    const int idx = blockIdx.x * 256 + threadIdx.x;
    const int t = idx >> 8;
    const int d = (idx & 255) * 4;
    const ushort4 xr = *(const ushort4*)(xnb + (size_t)t * DIM + d);
    float4 a;
    a.x = b2f(xr.x); a.y = b2f(xr.y); a.z = b2f(xr.z); a.w = b2f(xr.w);
    #pragma unroll
    for (int s = 0; s < NSLOT; ++s) {
        const float sc = sscore[(size_t)t * NSLOT + s];
        const ushort4 u = *(const ushort4*)(sbuf + ((size_t)t * NSLOT + s) * DIM + d);
        a.x += gelu_tanh(b2f(u.x)) * sc;
        a.y += gelu_tanh(b2f(u.y)) * sc;
        a.z += gelu_tanh(b2f(u.z)) * sc;
        a.w += gelu_tanh(b2f(u.w)) * sc;
    }
    ((float4*)y)[idx] = a;
}

extern "C" void kernel_launch(void* const* d_in, const int* in_sizes, int n_in,
                              void* d_out, int out_size, void* d_ws, size_t ws_size,
                              hipStream_t stream) {
    const float* x      = (const float*)d_in[0];
    const float* rms_w  = (const float*)d_in[1];
    const float* cent   = (const float*)d_in[2];
    const float* sW1    = (const float*)d_in[3];
    const float* sb1    = (const float*)d_in[4];
    const float* sW2    = (const float*)d_in[5];
    const float* sb2    = (const float*)d_in[6];
    const float* rW1    = (const float*)d_in[7];
    const float* rb1    = (const float*)d_in[8];
    const float* rW2    = (const float*)d_in[9];
    const float* rb2    = (const float*)d_in[10];

    float* y_out   = (float*)d_out;
    float* aff_out = (float*)d_out + (size_t)T_TOK * DIM;

    char* p = (char*)d_ws;
    size_t off = 0;
    auto take = [&](size_t b) {
        char* r = p + off;
        off += (b + 255) & ~(size_t)255;
        return r;
    };
    ushort* xnb    = (ushort*)take((size_t)T_TOK * DIM * 2);
    ushort* W1p    = (ushort*)take((size_t)N_E * DIM * HDIM * 2);
    ushort* W2p    = (ushort*)take((size_t)N_E * HDIM * DIM * 2);
    int*    counts = (int*)take(N_RT * sizeof(int));
    int*    lists  = (int*)take((size_t)N_RT * T_TOK * 4);
    float*  sscore = (float*)take((size_t)T_TOK * NSLOT * 4);
    int*    tk_e   = (int*)take((size_t)T_TOK * TOPK * 4);
    ushort* sbuf   = (ushort*)take(((size_t)T_TOK * NSLOT + TB) * DIM * 2);
    const bool slot_ok = (off <= ws_size);

    pack_weights<DIM, HDIM><<<dim3(64, N_E), dim3(256), 0, stream>>>(sW1, rW1, W1p);
    pack_weights<HDIM, DIM><<<dim3(64, N_E), dim3(256), 0, stream>>>(sW2, rW2, W2p);

    rms_router_kernel<<<dim3(T_TOK / 4), dim3(256), 0, stream>>>(
        x, rms_w, cent, xnb, aff_out, tk_e, sscore);

    scatter_kernel<<<dim3(N_RT), dim3(64), 0, stream>>>(tk_e, counts, lists);

    const int grid = 64 + 8 * MAXPB;
    if (slot_ok) {
        moe_mfma<false><<<dim3(grid), dim3(512), 0, stream>>>(
            xnb, W1p, W2p, sb1, sb2, rb1, rb2, counts, lists,
            sscore, sbuf, y_out);
        gather_kernel<<<dim3((T_TOK * DIM / 4) / 256), dim3(256), 0, stream>>>(
            sbuf, sscore, xnb, y_out);
    } else {
        residual_init<<<dim3((T_TOK * DIM / 4) / 256), dim3(256), 0, stream>>>(
            xnb, y_out);
        moe_mfma<true><<<dim3(grid), dim3(512), 0, stream>>>(
            xnb, W1p, W2p, sb1, sb2, rb1, rb2, counts, lists,
            sscore, sbuf, y_out);
    }
}

// Round 21
// 128.337 us; speedup vs baseline: 1.2048x; 1.0907x over previous
//
#include <hip/hip_runtime.h>
#include <hip/hip_bf16.h>
#include <math.h>

#define T_TOK 4096
#define DIM   1024
#define HDIM  256
#define N_SH  2
#define N_RT  32
#define N_E   34
#define TOPK  4
#define TB    128
#define MAXPB 200
#define NSLOT 6
#define OSW   34          // ostage row stride (32 cols + 2 pad)

typedef short bf16x8 __attribute__((ext_vector_type(8)));
typedef float f32x4  __attribute__((ext_vector_type(4)));
typedef unsigned short u16x8 __attribute__((ext_vector_type(8)));

__device__ __forceinline__ ushort f2b(float v) {
    __hip_bfloat16 h = __float2bfloat16(v);
    return *reinterpret_cast<const ushort*>(&h);
}
__device__ __forceinline__ float b2f(ushort u) {
    unsigned int x = ((unsigned int)u) << 16;
    return __uint_as_float(x);
}
__device__ __forceinline__ float gelu_tanh(float x) {
    float z = 0.7978845608028654f * (x + 0.044715f * x * x * x);
    float e = __expf(2.0f * z);
    float t = 1.0f - 2.0f / (e + 1.0f);
    return 0.5f * x * (1.0f + t);
}

// async global->LDS, 16B per lane; LDS dst wave-uniform base (+lane*16 by HW)
__device__ __forceinline__ void gload_lds16(const ushort* g, ushort* l) {
    __builtin_amdgcn_global_load_lds(
        (const __attribute__((address_space(1))) void*)g,
        (__attribute__((address_space(3))) void*)l,
        16, 0, 0);
}

#define SBAR() __builtin_amdgcn_sched_barrier(0)

// ---- pack weights: W1 (z=0) + W2 (z=1) in one dispatch, coalesced LDS-transpose ----
__global__ __launch_bounds__(256) void pack_weights(
    const float* __restrict__ sW1, const float* __restrict__ rW1,
    const float* __restrict__ sW2, const float* __restrict__ rW2,
    ushort* __restrict__ W1p, ushort* __restrict__ W2p)
{
    const int z = blockIdx.z;
    const int K = z ? HDIM : DIM;
    const int N = z ? DIM : HDIM;
    const int e = blockIdx.y;
    const float* srcS = z ? sW2 : sW1;
    const float* srcR = z ? rW2 : rW1;
    ushort* dst       = z ? W2p : W1p;
    const float* src = (e < N_SH) ? (srcS + (size_t)e * K * N)
                                  : (srcR + (size_t)(e - N_SH) * K * N);
    const int kt  = K / 32;
    const int k32 = blockIdx.x % kt;
    const int nc  = blockIdx.x / kt;
    const int tid = threadIdx.x;

    __shared__ ushort ls[32][137];

    #pragma unroll
    for (int it = 0; it < 4; ++it) {
        const int row = it * 8 + (tid >> 5);
        const int c4  = tid & 31;
        const float4 v = *(const float4*)(src + (size_t)(k32 * 32 + row) * N
                                          + nc * 128 + c4 * 4);
        ls[row][c4 * 4 + 0] = f2b(v.x);
        ls[row][c4 * 4 + 1] = f2b(v.y);
        ls[row][c4 * 4 + 2] = f2b(v.z);
        ls[row][c4 * 4 + 3] = f2b(v.w);
    }
    __syncthreads();

    #pragma unroll
    for (int it = 0; it < 2; ++it) {
        const int t8   = tid >> 5;
        const int lane = it * 32 + (tid & 31);
        const int l16 = lane & 15, lk = lane >> 4;
        u16x8 o;
        #pragma unroll
        for (int j = 0; j < 8; ++j)
            o[j] = ls[lk * 8 + j][t8 * 16 + l16];
        const size_t tile = (size_t)(nc * 8 + t8) * kt + k32;
        *(u16x8*)(dst + (size_t)e * K * N + tile * 512 + lane * 8) = o;
    }
}

// ---------------- RMSNorm + router, 16 tokens per block ----------------
// Wave w: RMS for tokens t0+w*4..+3; logits for experts w*8..+7 over all 16;
// softmax/top-4 for its own 4 tokens. Centroid traffic: 256 blocks x 128KB = 32MB.
__global__ __launch_bounds__(256) void rms_router_kernel(
    const float* __restrict__ x, const float* __restrict__ rms_w,
    const float* __restrict__ cent,
    ushort* __restrict__ xnb, float* __restrict__ aff_out,
    int* __restrict__ tk_e, float* __restrict__ sscore)
{
    const int t0  = blockIdx.x * 16;
    const int tid = threadIdx.x;
    const int wid = tid >> 6;
    const int lane = tid & 63;

    __shared__ float xsh[16][DIM];       // 64 KB
    __shared__ float logits[16][N_RT];   // 2 KB

    float4 wv4[4];
    #pragma unroll
    for (int q = 0; q < 4; ++q)
        wv4[q] = ((const float4*)rms_w)[lane + 64 * q];

    // ---- RMS: wave wid -> tokens t0 + wid*4 .. +3 ----
    #pragma unroll
    for (int j = 0; j < 4; ++j) {
        const int t = t0 + wid * 4 + j;
        float4 xv[4];
        float ss = 0.f;
        #pragma unroll
        for (int q = 0; q < 4; ++q) {
            xv[q] = ((const float4*)(x + (size_t)t * DIM))[lane + 64 * q];
            ss += xv[q].x*xv[q].x + xv[q].y*xv[q].y + xv[q].z*xv[q].z + xv[q].w*xv[q].w;
        }
        #pragma unroll
        for (int o = 32; o > 0; o >>= 1) ss += __shfl_down(ss, o);
        const float rstd = rsqrtf(__shfl(ss, 0) * (1.0f / (float)DIM) + 1e-6f);
        #pragma unroll
        for (int q = 0; q < 4; ++q) {
            float4 nv;
            nv.x = xv[q].x * rstd * wv4[q].x;
            nv.y = xv[q].y * rstd * wv4[q].y;
            nv.z = xv[q].z * rstd * wv4[q].z;
            nv.w = xv[q].w * rstd * wv4[q].w;
            ushort4 xb = make_ushort4(f2b(nv.x), f2b(nv.y), f2b(nv.z), f2b(nv.w));
            ((ushort4*)(xnb + (size_t)t * DIM))[lane + 64 * q] = xb;
            ((float4*)xsh[wid * 4 + j])[lane + 64 * q] = nv;
        }
    }
    __syncthreads();

    // ---- logits: wave wid -> experts wid*8 .. +7, all 16 tokens ----
    #pragma unroll
    for (int ei = 0; ei < 8; ++ei) {
        const int e = wid * 8 + ei;
        const float4* c4 = (const float4*)(cent + (size_t)e * DIM);
        float acc[16];
        #pragma unroll
        for (int tk = 0; tk < 16; ++tk) acc[tk] = 0.f;
        #pragma unroll
        for (int q = 0; q < 4; ++q) {
            const float4 cv = c4[lane + 64 * q];
            #pragma unroll
            for (int tk = 0; tk < 16; ++tk) {
                const float4 xq = ((const float4*)xsh[tk])[lane + 64 * q];
                acc[tk] += cv.x*xq.x + cv.y*xq.y + cv.z*xq.z + cv.w*xq.w;
            }
        }
        #pragma unroll
        for (int o = 32; o > 0; o >>= 1) {
            #pragma unroll
            for (int tk = 0; tk < 16; ++tk)
                acc[tk] += __shfl_down(acc[tk], o);
        }
        if (lane == 0) {
            #pragma unroll
            for (int tk = 0; tk < 16; ++tk) logits[tk][e] = acc[tk];
        }
    }
    __syncthreads();

    // ---- softmax + top-4: wave wid -> its 4 tokens ----
    #pragma unroll
    for (int j = 0; j < 4; ++j) {
        const int tk = wid * 4 + j;
        const int t  = t0 + tk;
        float v = (lane < N_RT) ? logits[tk][lane] : -INFINITY;
        float m = v;
        #pragma unroll
        for (int o = 32; o > 0; o >>= 1) m = fmaxf(m, __shfl_xor(m, o));
        float p = (lane < N_RT) ? expf(v - m) : 0.f;
        float s = p;
        #pragma unroll
        for (int o = 32; o > 0; o >>= 1) s += __shfl_xor(s, o);
        const float a = p / s;
        if (lane < N_RT) aff_out[(size_t)t * N_RT + lane] = a;
        if (lane < N_SH) sscore[(size_t)t * NSLOT + lane] = 1.f;

        float vv = (lane < N_RT) ? a : -1.f;
        #pragma unroll
        for (int it = 0; it < TOPK; ++it) {
            float mx = vv;
            #pragma unroll
            for (int o = 32; o > 0; o >>= 1) mx = fmaxf(mx, __shfl_xor(mx, o));
            unsigned long long msk = __ballot(vv == mx);
            int sel = __ffsll((long long)msk) - 1;
            sel = (sel < 0) ? 0 : (sel & (N_RT - 1));
            if (lane == 0) {
                tk_e[(size_t)t * TOPK + it] = sel;
                sscore[(size_t)t * NSLOT + 2 + it] = mx;
            }
            if (lane == sel) vv = -1.f;
        }
    }
}

// ---- scatter v2: 4 waves/block, two-pass (count -> prefix -> compact) ----
// Deterministic: wave w owns chunk w of tk_e; offsets from LDS prefix.
__global__ __launch_bounds__(256) void scatter_kernel(
    const int* __restrict__ tk_e, int* __restrict__ counts, int* __restrict__ lists)
{
    const int e    = blockIdx.x;
    const int tid  = threadIdx.x;
    const int wv   = tid >> 6;
    const int lane = tid & 63;
    const unsigned long long lt = (1ull << lane) - 1ull;
    const int CH = T_TOK * TOPK / 4;        // 4096 entries per wave
    const int base0 = wv * CH;

    __shared__ int wcnt[4];

    // pass 1: count matches in this wave's chunk
    int cnt = 0;
    for (int c = 0; c < CH; c += 256) {
        const int4 v = *(const int4*)(tk_e + base0 + c + lane * 4);
        cnt += __popcll(__ballot(v.x == e));
        cnt += __popcll(__ballot(v.y == e));
        cnt += __popcll(__ballot(v.z == e));
        cnt += __popcll(__ballot(v.w == e));
    }
    if (lane == 0) wcnt[wv] = cnt;
    __syncthreads();

    int base = 0;
    #pragma unroll
    for (int g = 0; g < 4; ++g)
        if (g < wv) base += wcnt[g];

    // pass 2: compact at precomputed offset
    int* lst = lists + (size_t)e * T_TOK;
    for (int c = 0; c < CH; c += 256) {
        const int4 v = *(const int4*)(tk_e + base0 + c + lane * 4);
        const bool p0 = (v.x == e), p1 = (v.y == e), p2 = (v.z == e), p3 = (v.w == e);
        const unsigned long long m0 = __ballot(p0);
        const unsigned long long m1 = __ballot(p1);
        const unsigned long long m2 = __ballot(p2);
        const unsigned long long m3 = __ballot(p3);
        const int c0 = __popcll(m0), c1 = __popcll(m1), c2 = __popcll(m2);
        if (p0) lst[base + __popcll(m0 & lt)] = base0 + c + lane * 4 + 0;
        if (p1) lst[base + c0 + __popcll(m1 & lt)] = base0 + c + lane * 4 + 1;
        if (p2) lst[base + c0 + c1 + __popcll(m2 & lt)] = base0 + c + lane * 4 + 2;
        if (p3) lst[base + c0 + c1 + c2 + __popcll(m3 & lt)] = base0 + c + lane * 4 + 3;
        base += c0 + c1 + c2 + __popcll(m3);
    }
    if (tid == 0) counts[e] = wcnt[0] + wcnt[1] + wcnt[2] + wcnt[3];
}

// ---- residual init (fallback path only): y = bf16(xn) ----
__global__ __launch_bounds__(256) void residual_init(
    const ushort* __restrict__ xnb, float* __restrict__ y)
{
    const int idx = blockIdx.x * 256 + threadIdx.x;
    const ushort4 xr = *(const ushort4*)(xnb + (size_t)idx * 4);
    float4 a;
    a.x = b2f(xr.x); a.y = b2f(xr.y); a.z = b2f(xr.z); a.w = b2f(xr.w);
    ((float4*)y)[idx] = a;
}

// ---------------- fused 2-layer expert MLP (r20-exact, verified best) ----------------
template<bool ATOMIC>
__global__ __launch_bounds__(512, 2) void moe_mfma(
    const ushort* __restrict__ xnb,
    const ushort* __restrict__ W1p, const ushort* __restrict__ W2p,
    const float* __restrict__ sb1, const float* __restrict__ sb2,
    const float* __restrict__ rb1, const float* __restrict__ rb2,
    const int* __restrict__ counts, const int* __restrict__ lists,
    const float* __restrict__ sscore,
    ushort* __restrict__ sbuf, float* __restrict__ y)
{
    const int bi  = blockIdx.x;
    const int tid = threadIdx.x;

    __shared__ int    toks[TB];
    __shared__ int    orow[TB];
    __shared__ float  tscs[TB];
    __shared__ ushort hlds[TB * HDIM];          // 64 KB, XOR-swizzled, stride 512B
    __shared__ ushort astage[3 * 4096];         // 24 KB: [3 bufs][128 tok x 32 dims]
    __shared__ ushort ostage[8 * 64 * OSW];     // 34.8 KB per-wave repack

    int e_full;
    const float *b1, *b2;

    if (bi < 64) {                            // shared experts: 32 tiles x 2
        e_full = bi >> 5;
        const int tile = bi & 31;
        if (tid < TB) {
            const int t = tile * TB + tid;
            toks[tid] = t;
            orow[tid] = ATOMIC ? t : t * NSLOT + e_full;
            tscs[tid] = 1.f;
        }
        b1 = sb1 + e_full * HDIM;  b2 = sb2 + e_full * DIM;
    } else {                                  // routed: bucket walk over counts
        const int j = bi - 64;
        const int b = j & 7, pos = j >> 3;
        int e = -1, tile = 0, accum = 0;
        #pragma unroll
        for (int g = 0; g < 4; ++g) {
            const int eg = b + 8 * g;
            const int tg = (counts[eg] + TB - 1) / TB;
            if (e < 0 && pos < accum + tg) { e = eg; tile = pos - accum; }
            accum += tg;
        }
        if (e < 0) return;
        e_full = N_SH + e;
        const int cnt = counts[e];
        if (tid < TB) {
            const int idx = tile * TB + tid;
            if (idx < cnt) {
                const int lv = lists[(size_t)e * T_TOK + idx];
                const int t = (lv >> 2) & (T_TOK - 1);
                toks[tid] = t;
                orow[tid] = ATOMIC ? t : t * NSLOT + 2 + (lv & 3);
                tscs[tid] = ATOMIC ? sscore[(size_t)t * NSLOT + 2 + (lv & 3)] : 0.f;
            } else {
                toks[tid] = 0;
                orow[tid] = ATOMIC ? 0 : T_TOK * NSLOT;   // dummy row
                tscs[tid] = 0.f;
            }
        }
        b1 = rb1 + e * HDIM;  b2 = rb2 + e * DIM;
    }
    __syncthreads();

    const int w = tid >> 6, lane = tid & 63;
    const int l16 = lane & 15, lk = lane >> 4;
    const int mh = w >> 2;          // token half (64 rows)
    const int nq = w & 3;           // N quarter (64 cols)

    const ushort* W1e = W1p + (size_t)e_full * DIM * HDIM;
    const ushort* W2e = W2p + (size_t)e_full * HDIM * DIM;

    // ---- phase 1: C1[128,256] = X @ W1, A triple-buffered LDS, counted vmcnt ----
    {
        const ushort* asrc = xnb + (size_t)toks[w * 16 + (lane >> 2)] * DIM
                             + (lane & 3) * 8;
        SBAR();
        gload_lds16(asrc,      astage + 0 * 4096 + w * 512);
        gload_lds16(asrc + 32, astage + 1 * 4096 + w * 512);
        SBAR();

        const ushort* bbase[4];
        #pragma unroll
        for (int ni = 0; ni < 4; ++ni)
            bbase[ni] = W1e + (size_t)((nq * 4 + ni) * 32) * 512 + lane * 8;

        f32x4 acc[4][4];
        #pragma unroll
        for (int mi = 0; mi < 4; ++mi)
            #pragma unroll
            for (int ni = 0; ni < 4; ++ni) acc[mi][ni] = (f32x4){0.f,0.f,0.f,0.f};

        bf16x8 bc[4];
        #pragma unroll
        for (int ni = 0; ni < 4; ++ni) bc[ni] = *(const bf16x8*)bbase[ni];

        asm volatile("s_waitcnt vmcnt(5)" ::: "memory");
        __builtin_amdgcn_s_barrier();
        SBAR();

        #pragma unroll 2
        for (int k32 = 0; k32 < 32; ++k32) {
            const int cur = k32 % 3;
            bf16x8 a[4], bn[4];
            #pragma unroll
            for (int mi = 0; mi < 4; ++mi) {
                const int tloc = mh * 64 + mi * 16 + l16;
                a[mi] = *(const bf16x8*)(astage + cur * 4096 + tloc * 32 + lk * 8);
            }
            if (k32 < 31) {
                #pragma unroll
                for (int ni = 0; ni < 4; ++ni)
                    bn[ni] = *(const bf16x8*)(bbase[ni] + (size_t)(k32 + 1) * 512);
            }
            #pragma unroll
            for (int ni = 0; ni < 4; ++ni)
                #pragma unroll
                for (int mi = 0; mi < 4; ++mi)
                    acc[mi][ni] = __builtin_amdgcn_mfma_f32_16x16x32_bf16(a[mi], bc[ni], acc[mi][ni], 0, 0, 0);
            if (k32 < 31) {
                #pragma unroll
                for (int ni = 0; ni < 4; ++ni) bc[ni] = bn[ni];
            }

            if (k32 < 30) {
                asm volatile("s_waitcnt lgkmcnt(0)" ::: "memory");
                SBAR();
                gload_lds16(asrc + (k32 + 2) * 32,
                            astage + ((k32 + 2) % 3) * 4096 + w * 512);
                SBAR();
                asm volatile("s_waitcnt vmcnt(5)" ::: "memory");
                __builtin_amdgcn_s_barrier();
                SBAR();
            } else if (k32 == 30) {
                asm volatile("s_waitcnt vmcnt(4)" ::: "memory");
                __builtin_amdgcn_s_barrier();
                SBAR();
            }
        }

        // h = bf16(C1 + b1) -> swizzled LDS [128 rows][256 cols]
        #pragma unroll
        for (int ni = 0; ni < 4; ++ni) {
            const int n = nq * 64 + ni * 16 + l16;
            const float bv = b1[n];
            #pragma unroll
            for (int mi = 0; mi < 4; ++mi) {
                #pragma unroll
                for (int r = 0; r < 4; ++r) {
                    const int m = mh * 64 + mi * 16 + lk * 4 + r;
                    const int byte = (m * (HDIM * 2) + n * 2) ^ ((m & 7) << 4);
                    *(ushort*)((char*)hlds + byte) = f2b(acc[mi][ni][r] + bv);
                }
            }
        }
    }
    __syncthreads();

    // ---- phase 2: C2[128,1024] = h @ W2, 4 jc chunks x 8 k-steps ----
    {
        for (int jc = 0; jc < 4; ++jc) {
            f32x4 acc2[4][4];
            #pragma unroll
            for (int mi = 0; mi < 4; ++mi)
                #pragma unroll
                for (int ni = 0; ni < 4; ++ni) acc2[mi][ni] = (f32x4){0.f,0.f,0.f,0.f};

            const ushort* b2base[4];
            #pragma unroll
            for (int ni = 0; ni < 4; ++ni)
                b2base[ni] = W2e + (size_t)((jc * 16 + nq * 4 + ni) * 8) * 512 + lane * 8;

            bf16x8 bc2[4];
            #pragma unroll
            for (int ni = 0; ni < 4; ++ni) bc2[ni] = *(const bf16x8*)b2base[ni];

            #pragma unroll
            for (int k32 = 0; k32 < 8; ++k32) {
                bf16x8 a2[4];
                #pragma unroll
                for (int mi = 0; mi < 4; ++mi) {
                    const int m = mh * 64 + mi * 16 + l16;
                    const int byte = (m * (HDIM * 2) + (k32 * 32 + lk * 8) * 2) ^ ((m & 7) << 4);
                    a2[mi] = *(const bf16x8*)((const char*)hlds + byte);
                }
                bf16x8 bn2[4];
                if (k32 < 7) {
                    #pragma unroll
                    for (int ni = 0; ni < 4; ++ni)
                        bn2[ni] = *(const bf16x8*)(b2base[ni] + (size_t)(k32 + 1) * 512);
                }
                #pragma unroll
                for (int ni = 0; ni < 4; ++ni)
                    #pragma unroll
                    for (int mi = 0; mi < 4; ++mi)
                        acc2[mi][ni] = __builtin_amdgcn_mfma_f32_16x16x32_bf16(a2[mi], bc2[ni], acc2[mi][ni], 0, 0, 0);
                if (k32 < 7) {
                    #pragma unroll
                    for (int ni = 0; ni < 4; ++ni) bc2[ni] = bn2[ni];
                }
            }

            if (ATOMIC) {
                #pragma unroll
                for (int ni = 0; ni < 4; ++ni) {
                    const int n = jc * 256 + nq * 64 + ni * 16 + l16;
                    const float bv = b2[n];
                    #pragma unroll
                    for (int mi = 0; mi < 4; ++mi)
                        #pragma unroll
                        for (int r = 0; r < 4; ++r) {
                            const int m = mi * 16 + lk * 4 + r;
                            const float val = gelu_tanh(acc2[mi][ni][r] + bv) * tscs[mh * 64 + m];
                            atomicAdd(&y[(size_t)orow[mh * 64 + m] * DIM + n], val);
                        }
                }
            } else {
                ushort* os = ostage + w * (64 * OSW);
                #pragma unroll
                for (int p = 0; p < 2; ++p) {
                    asm volatile("s_waitcnt lgkmcnt(0)" ::: "memory");
                    #pragma unroll
                    for (int q = 0; q < 2; ++q) {
                        const int ni = p * 2 + q;
                        const float bv = b2[jc * 256 + nq * 64 + ni * 16 + l16];
                        #pragma unroll
                        for (int mi = 0; mi < 4; ++mi)
                            #pragma unroll
                            for (int r = 0; r < 4; ++r) {
                                const int m = mi * 16 + lk * 4 + r;
                                os[m * OSW + q * 16 + l16] = f2b(acc2[mi][ni][r] + bv);
                            }
                    }
                    asm volatile("s_waitcnt lgkmcnt(0)" ::: "memory");
                    #pragma unroll
                    for (int rr = 0; rr < 4; ++rr) {
                        const int m  = rr * 16 + (lane >> 2);
                        const int nl = (lane & 3) * 8;
                        u16x8 vv = *(const u16x8*)(os + m * OSW + nl);
                        *(u16x8*)(sbuf + (size_t)orow[mh * 64 + m] * DIM
                                  + jc * 256 + nq * 64 + p * 32 + nl) = vv;
                    }
                }
            }
        }
    }
}

// ---------------- gather: y = bf16(xn) + sum_s gelu(slot)*score ----------------
__global__ __launch_bounds__(256) void gather_kernel(
    const ushort* __restrict__ sbuf, const float* __restrict__ sscore,
    const ushort* __restrict__ xnb, float* __restrict__ y)
{
    const int idx = blockIdx.x * 256 + threadIdx.x;
    const int t = idx >> 8;
    const int d = (idx & 255) * 4;
    const ushort4 xr = *(const ushort4*)(xnb + (size_t)t * DIM + d);
    float4 a;
    a.x = b2f(xr.x); a.y = b2f(xr.y); a.z = b2f(xr.z); a.w = b2f(xr.w);
    #pragma unroll
    for (int s = 0; s < NSLOT; ++s) {
        const float sc = sscore[(size_t)t * NSLOT + s];
        const ushort4 u = *(const ushort4*)(sbuf + ((size_t)t * NSLOT + s) * DIM + d);
        a.x += gelu_tanh(b2f(u.x)) * sc;
        a.y += gelu_tanh(b2f(u.y)) * sc;
        a.z += gelu_tanh(b2f(u.z)) * sc;
        a.w += gelu_tanh(b2f(u.w)) * sc;
    }
    ((float4*)y)[idx] = a;
}

extern "C" void kernel_launch(void* const* d_in, const int* in_sizes, int n_in,
                              void* d_out, int out_size, void* d_ws, size_t ws_size,
                              hipStream_t stream) {
    const float* x      = (const float*)d_in[0];
    const float* rms_w  = (const float*)d_in[1];
    const float* cent   = (const float*)d_in[2];
    const float* sW1    = (const float*)d_in[3];
    const float* sb1    = (const float*)d_in[4];
    const float* sW2    = (const float*)d_in[5];
    const float* sb2    = (const float*)d_in[6];
    const float* rW1    = (const float*)d_in[7];
    const float* rb1    = (const float*)d_in[8];
    const float* rW2    = (const float*)d_in[9];
    const float* rb2    = (const float*)d_in[10];

    float* y_out   = (float*)d_out;
    float* aff_out = (float*)d_out + (size_t)T_TOK * DIM;

    char* p = (char*)d_ws;
    size_t off = 0;
    auto take = [&](size_t b) {
        char* r = p + off;
        off += (b + 255) & ~(size_t)255;
        return r;
    };
    ushort* xnb    = (ushort*)take((size_t)T_TOK * DIM * 2);
    ushort* W1p    = (ushort*)take((size_t)N_E * DIM * HDIM * 2);
    ushort* W2p    = (ushort*)take((size_t)N_E * HDIM * DIM * 2);
    int*    counts = (int*)take(N_RT * sizeof(int));
    int*    lists  = (int*)take((size_t)N_RT * T_TOK * 4);
    float*  sscore = (float*)take((size_t)T_TOK * NSLOT * 4);
    int*    tk_e   = (int*)take((size_t)T_TOK * TOPK * 4);
    ushort* sbuf   = (ushort*)take(((size_t)T_TOK * NSLOT + TB) * DIM * 2);
    const bool slot_ok = (off <= ws_size);

    pack_weights<<<dim3(64, N_E, 2), dim3(256), 0, stream>>>(
        sW1, rW1, sW2, rW2, W1p, W2p);

    rms_router_kernel<<<dim3(T_TOK / 16), dim3(256), 0, stream>>>(
        x, rms_w, cent, xnb, aff_out, tk_e, sscore);

    scatter_kernel<<<dim3(N_RT), dim3(256), 0, stream>>>(tk_e, counts, lists);

    const int grid = 64 + 8 * MAXPB;
    if (slot_ok) {
        moe_mfma<false><<<dim3(grid), dim3(512), 0, stream>>>(
            xnb, W1p, W2p, sb1, sb2, rb1, rb2, counts, lists,
            sscore, sbuf, y_out);
        gather_kernel<<<dim3((T_TOK * DIM / 4) / 256), dim3(256), 0, stream>>>(
            sbuf, sscore, xnb, y_out);
    } else {
        residual_init<<<dim3((T_TOK * DIM / 4) / 256), dim3(256), 0, stream>>>(
            xnb, y_out);
        moe_mfma<true><<<dim3(grid), dim3(512), 0, stream>>>(
            xnb, W1p, W2p, sb1, sb2, rb1, rb2, counts, lists,
            sscore, sbuf, y_out);
    }
}

// Round 22
// 122.425 us; speedup vs baseline: 1.2630x; 1.0483x over previous
//
#include <hip/hip_runtime.h>
#include <hip/hip_bf16.h>
#include <math.h>

#define T_TOK 4096
#define DIM   1024
#define HDIM  256
#define N_SH  2
#define N_RT  32
#define N_E   34
#define TOPK  4
#define TB    128
#define MAXPB 200
#define NSLOT 6
#define OSW   34          // ostage row stride (32 cols + 2 pad)

typedef short bf16x8 __attribute__((ext_vector_type(8)));
typedef float f32x4  __attribute__((ext_vector_type(4)));
typedef unsigned short u16x8 __attribute__((ext_vector_type(8)));

__device__ __forceinline__ ushort f2b(float v) {
    __hip_bfloat16 h = __float2bfloat16(v);
    return *reinterpret_cast<const ushort*>(&h);
}
__device__ __forceinline__ float b2f(ushort u) {
    unsigned int x = ((unsigned int)u) << 16;
    return __uint_as_float(x);
}
__device__ __forceinline__ float gelu_tanh(float x) {
    float z = 0.7978845608028654f * (x + 0.044715f * x * x * x);
    float e = __expf(2.0f * z);
    float t = 1.0f - 2.0f / (e + 1.0f);
    return 0.5f * x * (1.0f + t);
}

// async global->LDS, 16B per lane; LDS dst wave-uniform base (+lane*16 by HW)
__device__ __forceinline__ void gload_lds16(const ushort* g, ushort* l) {
    __builtin_amdgcn_global_load_lds(
        (const __attribute__((address_space(1))) void*)g,
        (__attribute__((address_space(3))) void*)l,
        16, 0, 0);
}

#define SBAR() __builtin_amdgcn_sched_barrier(0)

// ---- pack weights: W1 (z=0) + W2 (z=1) in one dispatch, coalesced LDS-transpose ----
__global__ __launch_bounds__(256) void pack_weights(
    const float* __restrict__ sW1, const float* __restrict__ rW1,
    const float* __restrict__ sW2, const float* __restrict__ rW2,
    ushort* __restrict__ W1p, ushort* __restrict__ W2p)
{
    const int z = blockIdx.z;
    const int K = z ? HDIM : DIM;
    const int N = z ? DIM : HDIM;
    const int e = blockIdx.y;
    const float* srcS = z ? sW2 : sW1;
    const float* srcR = z ? rW2 : rW1;
    ushort* dst       = z ? W2p : W1p;
    const float* src = (e < N_SH) ? (srcS + (size_t)e * K * N)
                                  : (srcR + (size_t)(e - N_SH) * K * N);
    const int kt  = K / 32;
    const int k32 = blockIdx.x % kt;
    const int nc  = blockIdx.x / kt;
    const int tid = threadIdx.x;

    __shared__ ushort ls[32][137];

    #pragma unroll
    for (int it = 0; it < 4; ++it) {
        const int row = it * 8 + (tid >> 5);
        const int c4  = tid & 31;
        const float4 v = *(const float4*)(src + (size_t)(k32 * 32 + row) * N
                                          + nc * 128 + c4 * 4);
        ls[row][c4 * 4 + 0] = f2b(v.x);
        ls[row][c4 * 4 + 1] = f2b(v.y);
        ls[row][c4 * 4 + 2] = f2b(v.z);
        ls[row][c4 * 4 + 3] = f2b(v.w);
    }
    __syncthreads();

    #pragma unroll
    for (int it = 0; it < 2; ++it) {
        const int t8   = tid >> 5;
        const int lane = it * 32 + (tid & 31);
        const int l16 = lane & 15, lk = lane >> 4;
        u16x8 o;
        #pragma unroll
        for (int j = 0; j < 8; ++j)
            o[j] = ls[lk * 8 + j][t8 * 16 + l16];
        const size_t tile = (size_t)(nc * 8 + t8) * kt + k32;
        *(u16x8*)(dst + (size_t)e * K * N + tile * 512 + lane * 8) = o;
    }
}

// ---------------- RMSNorm + router, 8 tokens per block ----------------
// Wave w: RMS for tokens t0+w*2..+1; logits for experts w*8..+7 over all 8;
// softmax/top-4 for its own 2 tokens. 512 blocks -> 2 blocks/CU, 2 waves/SIMD.
__global__ __launch_bounds__(256) void rms_router_kernel(
    const float* __restrict__ x, const float* __restrict__ rms_w,
    const float* __restrict__ cent,
    ushort* __restrict__ xnb, float* __restrict__ aff_out,
    int* __restrict__ tk_e, float* __restrict__ sscore)
{
    const int t0  = blockIdx.x * 8;
    const int tid = threadIdx.x;
    const int wid = tid >> 6;
    const int lane = tid & 63;

    __shared__ float xsh[8][DIM];        // 32 KB
    __shared__ float logits[8][N_RT];    // 1 KB

    float4 wv4[4];
    #pragma unroll
    for (int q = 0; q < 4; ++q)
        wv4[q] = ((const float4*)rms_w)[lane + 64 * q];

    // ---- RMS: wave wid -> tokens t0 + wid*2 .. +1 ----
    #pragma unroll
    for (int j = 0; j < 2; ++j) {
        const int t = t0 + wid * 2 + j;
        float4 xv[4];
        float ss = 0.f;
        #pragma unroll
        for (int q = 0; q < 4; ++q) {
            xv[q] = ((const float4*)(x + (size_t)t * DIM))[lane + 64 * q];
            ss += xv[q].x*xv[q].x + xv[q].y*xv[q].y + xv[q].z*xv[q].z + xv[q].w*xv[q].w;
        }
        #pragma unroll
        for (int o = 32; o > 0; o >>= 1) ss += __shfl_down(ss, o);
        const float rstd = rsqrtf(__shfl(ss, 0) * (1.0f / (float)DIM) + 1e-6f);
        #pragma unroll
        for (int q = 0; q < 4; ++q) {
            float4 nv;
            nv.x = xv[q].x * rstd * wv4[q].x;
            nv.y = xv[q].y * rstd * wv4[q].y;
            nv.z = xv[q].z * rstd * wv4[q].z;
            nv.w = xv[q].w * rstd * wv4[q].w;
            ushort4 xb = make_ushort4(f2b(nv.x), f2b(nv.y), f2b(nv.z), f2b(nv.w));
            ((ushort4*)(xnb + (size_t)t * DIM))[lane + 64 * q] = xb;
            ((float4*)xsh[wid * 2 + j])[lane + 64 * q] = nv;
        }
    }
    __syncthreads();

    // ---- logits: wave wid -> experts wid*8 .. +7, all 8 tokens ----
    #pragma unroll
    for (int ei = 0; ei < 8; ++ei) {
        const int e = wid * 8 + ei;
        const float4* c4 = (const float4*)(cent + (size_t)e * DIM);
        float acc[8];
        #pragma unroll
        for (int tk = 0; tk < 8; ++tk) acc[tk] = 0.f;
        #pragma unroll
        for (int q = 0; q < 4; ++q) {
            const float4 cv = c4[lane + 64 * q];
            #pragma unroll
            for (int tk = 0; tk < 8; ++tk) {
                const float4 xq = ((const float4*)xsh[tk])[lane + 64 * q];
                acc[tk] += cv.x*xq.x + cv.y*xq.y + cv.z*xq.z + cv.w*xq.w;
            }
        }
        #pragma unroll
        for (int o = 32; o > 0; o >>= 1) {
            #pragma unroll
            for (int tk = 0; tk < 8; ++tk)
                acc[tk] += __shfl_down(acc[tk], o);
        }
        if (lane == 0) {
            #pragma unroll
            for (int tk = 0; tk < 8; ++tk) logits[tk][e] = acc[tk];
        }
    }
    __syncthreads();

    // ---- softmax + top-4: wave wid -> its 2 tokens ----
    #pragma unroll
    for (int j = 0; j < 2; ++j) {
        const int tk = wid * 2 + j;
        const int t  = t0 + tk;
        float v = (lane < N_RT) ? logits[tk][lane] : -INFINITY;
        float m = v;
        #pragma unroll
        for (int o = 32; o > 0; o >>= 1) m = fmaxf(m, __shfl_xor(m, o));
        float p = (lane < N_RT) ? expf(v - m) : 0.f;
        float s = p;
        #pragma unroll
        for (int o = 32; o > 0; o >>= 1) s += __shfl_xor(s, o);
        const float a = p / s;
        if (lane < N_RT) aff_out[(size_t)t * N_RT + lane] = a;
        if (lane < N_SH) sscore[(size_t)t * NSLOT + lane] = 1.f;

        float vv = (lane < N_RT) ? a : -1.f;
        #pragma unroll
        for (int it = 0; it < TOPK; ++it) {
            float mx = vv;
            #pragma unroll
            for (int o = 32; o > 0; o >>= 1) mx = fmaxf(mx, __shfl_xor(mx, o));
            unsigned long long msk = __ballot(vv == mx);
            int sel = __ffsll((long long)msk) - 1;
            sel = (sel < 0) ? 0 : (sel & (N_RT - 1));
            if (lane == 0) {
                tk_e[(size_t)t * TOPK + it] = sel;
                sscore[(size_t)t * NSLOT + 2 + it] = mx;
            }
            if (lane == sel) vv = -1.f;
        }
    }
}

// ---- scatter v2: 4 waves/block, two-pass (count -> prefix -> compact) ----
__global__ __launch_bounds__(256) void scatter_kernel(
    const int* __restrict__ tk_e, int* __restrict__ counts, int* __restrict__ lists)
{
    const int e    = blockIdx.x;
    const int tid  = threadIdx.x;
    const int wv   = tid >> 6;
    const int lane = tid & 63;
    const unsigned long long lt = (1ull << lane) - 1ull;
    const int CH = T_TOK * TOPK / 4;        // 4096 entries per wave
    const int base0 = wv * CH;

    __shared__ int wcnt[4];

    int cnt = 0;
    for (int c = 0; c < CH; c += 256) {
        const int4 v = *(const int4*)(tk_e + base0 + c + lane * 4);
        cnt += __popcll(__ballot(v.x == e));
        cnt += __popcll(__ballot(v.y == e));
        cnt += __popcll(__ballot(v.z == e));
        cnt += __popcll(__ballot(v.w == e));
    }
    if (lane == 0) wcnt[wv] = cnt;
    __syncthreads();

    int base = 0;
    #pragma unroll
    for (int g = 0; g < 4; ++g)
        if (g < wv) base += wcnt[g];

    int* lst = lists + (size_t)e * T_TOK;
    for (int c = 0; c < CH; c += 256) {
        const int4 v = *(const int4*)(tk_e + base0 + c + lane * 4);
        const bool p0 = (v.x == e), p1 = (v.y == e), p2 = (v.z == e), p3 = (v.w == e);
        const unsigned long long m0 = __ballot(p0);
        const unsigned long long m1 = __ballot(p1);
        const unsigned long long m2 = __ballot(p2);
        const unsigned long long m3 = __ballot(p3);
        const int c0 = __popcll(m0), c1 = __popcll(m1), c2 = __popcll(m2);
        if (p0) lst[base + __popcll(m0 & lt)] = base0 + c + lane * 4 + 0;
        if (p1) lst[base + c0 + __popcll(m1 & lt)] = base0 + c + lane * 4 + 1;
        if (p2) lst[base + c0 + c1 + __popcll(m2 & lt)] = base0 + c + lane * 4 + 2;
        if (p3) lst[base + c0 + c1 + c2 + __popcll(m3 & lt)] = base0 + c + lane * 4 + 3;
        base += c0 + c1 + c2 + __popcll(m3);
    }
    if (tid == 0) counts[e] = wcnt[0] + wcnt[1] + wcnt[2] + wcnt[3];
}

// ---- residual init (fallback path only): y = bf16(xn) ----
__global__ __launch_bounds__(256) void residual_init(
    const ushort* __restrict__ xnb, float* __restrict__ y)
{
    const int idx = blockIdx.x * 256 + threadIdx.x;
    const ushort4 xr = *(const ushort4*)(xnb + (size_t)idx * 4);
    float4 a;
    a.x = b2f(xr.x); a.y = b2f(xr.y); a.z = b2f(xr.z); a.w = b2f(xr.w);
    ((float4*)y)[idx] = a;
}

// ---------------- fused 2-layer expert MLP (r20-exact, verified best) ----------------
template<bool ATOMIC>
__global__ __launch_bounds__(512, 2) void moe_mfma(
    const ushort* __restrict__ xnb,
    const ushort* __restrict__ W1p, const ushort* __restrict__ W2p,
    const float* __restrict__ sb1, const float* __restrict__ sb2,
    const float* __restrict__ rb1, const float* __restrict__ rb2,
    const int* __restrict__ counts, const int* __restrict__ lists,
    const float* __restrict__ sscore,
    ushort* __restrict__ sbuf, float* __restrict__ y)
{
    const int bi  = blockIdx.x;
    const int tid = threadIdx.x;

    __shared__ int    toks[TB];
    __shared__ int    orow[TB];
    __shared__ float  tscs[TB];
    __shared__ ushort hlds[TB * HDIM];          // 64 KB, XOR-swizzled, stride 512B
    __shared__ ushort astage[3 * 4096];         // 24 KB: [3 bufs][128 tok x 32 dims]
    __shared__ ushort ostage[8 * 64 * OSW];     // 34.8 KB per-wave repack

    int e_full;
    const float *b1, *b2;

    if (bi < 64) {                            // shared experts: 32 tiles x 2
        e_full = bi >> 5;
        const int tile = bi & 31;
        if (tid < TB) {
            const int t = tile * TB + tid;
            toks[tid] = t;
            orow[tid] = ATOMIC ? t : t * NSLOT + e_full;
            tscs[tid] = 1.f;
        }
        b1 = sb1 + e_full * HDIM;  b2 = sb2 + e_full * DIM;
    } else {                                  // routed: bucket walk over counts
        const int j = bi - 64;
        const int b = j & 7, pos = j >> 3;
        int e = -1, tile = 0, accum = 0;
        #pragma unroll
        for (int g = 0; g < 4; ++g) {
            const int eg = b + 8 * g;
            const int tg = (counts[eg] + TB - 1) / TB;
            if (e < 0 && pos < accum + tg) { e = eg; tile = pos - accum; }
            accum += tg;
        }
        if (e < 0) return;
        e_full = N_SH + e;
        const int cnt = counts[e];
        if (tid < TB) {
            const int idx = tile * TB + tid;
            if (idx < cnt) {
                const int lv = lists[(size_t)e * T_TOK + idx];
                const int t = (lv >> 2) & (T_TOK - 1);
                toks[tid] = t;
                orow[tid] = ATOMIC ? t : t * NSLOT + 2 + (lv & 3);
                tscs[tid] = ATOMIC ? sscore[(size_t)t * NSLOT + 2 + (lv & 3)] : 0.f;
            } else {
                toks[tid] = 0;
                orow[tid] = ATOMIC ? 0 : T_TOK * NSLOT;   // dummy row
                tscs[tid] = 0.f;
            }
        }
        b1 = rb1 + e * HDIM;  b2 = rb2 + e * DIM;
    }
    __syncthreads();

    const int w = tid >> 6, lane = tid & 63;
    const int l16 = lane & 15, lk = lane >> 4;
    const int mh = w >> 2;          // token half (64 rows)
    const int nq = w & 3;           // N quarter (64 cols)

    const ushort* W1e = W1p + (size_t)e_full * DIM * HDIM;
    const ushort* W2e = W2p + (size_t)e_full * HDIM * DIM;

    // ---- phase 1: C1[128,256] = X @ W1, A triple-buffered LDS, counted vmcnt ----
    {
        const ushort* asrc = xnb + (size_t)toks[w * 16 + (lane >> 2)] * DIM
                             + (lane & 3) * 8;
        SBAR();
        gload_lds16(asrc,      astage + 0 * 4096 + w * 512);
        gload_lds16(asrc + 32, astage + 1 * 4096 + w * 512);
        SBAR();

        const ushort* bbase[4];
        #pragma unroll
        for (int ni = 0; ni < 4; ++ni)
            bbase[ni] = W1e + (size_t)((nq * 4 + ni) * 32) * 512 + lane * 8;

        f32x4 acc[4][4];
        #pragma unroll
        for (int mi = 0; mi < 4; ++mi)
            #pragma unroll
            for (int ni = 0; ni < 4; ++ni) acc[mi][ni] = (f32x4){0.f,0.f,0.f,0.f};

        bf16x8 bc[4];
        #pragma unroll
        for (int ni = 0; ni < 4; ++ni) bc[ni] = *(const bf16x8*)bbase[ni];

        asm volatile("s_waitcnt vmcnt(5)" ::: "memory");
        __builtin_amdgcn_s_barrier();
        SBAR();

        #pragma unroll 2
        for (int k32 = 0; k32 < 32; ++k32) {
            const int cur = k32 % 3;
            bf16x8 a[4], bn[4];
            #pragma unroll
            for (int mi = 0; mi < 4; ++mi) {
                const int tloc = mh * 64 + mi * 16 + l16;
                a[mi] = *(const bf16x8*)(astage + cur * 4096 + tloc * 32 + lk * 8);
            }
            if (k32 < 31) {
                #pragma unroll
                for (int ni = 0; ni < 4; ++ni)
                    bn[ni] = *(const bf16x8*)(bbase[ni] + (size_t)(k32 + 1) * 512);
            }
            #pragma unroll
            for (int ni = 0; ni < 4; ++ni)
                #pragma unroll
                for (int mi = 0; mi < 4; ++mi)
                    acc[mi][ni] = __builtin_amdgcn_mfma_f32_16x16x32_bf16(a[mi], bc[ni], acc[mi][ni], 0, 0, 0);
            if (k32 < 31) {
                #pragma unroll
                for (int ni = 0; ni < 4; ++ni) bc[ni] = bn[ni];
            }

            if (k32 < 30) {
                asm volatile("s_waitcnt lgkmcnt(0)" ::: "memory");
                SBAR();
                gload_lds16(asrc + (k32 + 2) * 32,
                            astage + ((k32 + 2) % 3) * 4096 + w * 512);
                SBAR();
                asm volatile("s_waitcnt vmcnt(5)" ::: "memory");
                __builtin_amdgcn_s_barrier();
                SBAR();
            } else if (k32 == 30) {
                asm volatile("s_waitcnt vmcnt(4)" ::: "memory");
                __builtin_amdgcn_s_barrier();
                SBAR();
            }
        }

        // h = bf16(C1 + b1) -> swizzled LDS [128 rows][256 cols]
        #pragma unroll
        for (int ni = 0; ni < 4; ++ni) {
            const int n = nq * 64 + ni * 16 + l16;
            const float bv = b1[n];
            #pragma unroll
            for (int mi = 0; mi < 4; ++mi) {
                #pragma unroll
                for (int r = 0; r < 4; ++r) {
                    const int m = mh * 64 + mi * 16 + lk * 4 + r;
                    const int byte = (m * (HDIM * 2) + n * 2) ^ ((m & 7) << 4);
                    *(ushort*)((char*)hlds + byte) = f2b(acc[mi][ni][r] + bv);
                }
            }
        }
    }
    __syncthreads();

    // ---- phase 2: C2[128,1024] = h @ W2, 4 jc chunks x 8 k-steps ----
    {
        for (int jc = 0; jc < 4; ++jc) {
            f32x4 acc2[4][4];
            #pragma unroll
            for (int mi = 0; mi < 4; ++mi)
                #pragma unroll
                for (int ni = 0; ni < 4; ++ni) acc2[mi][ni] = (f32x4){0.f,0.f,0.f,0.f};

            const ushort* b2base[4];
            #pragma unroll
            for (int ni = 0; ni < 4; ++ni)
                b2base[ni] = W2e + (size_t)((jc * 16 + nq * 4 + ni) * 8) * 512 + lane * 8;

            bf16x8 bc2[4];
            #pragma unroll
            for (int ni = 0; ni < 4; ++ni) bc2[ni] = *(const bf16x8*)b2base[ni];

            #pragma unroll
            for (int k32 = 0; k32 < 8; ++k32) {
                bf16x8 a2[4];
                #pragma unroll
                for (int mi = 0; mi < 4; ++mi) {
                    const int m = mh * 64 + mi * 16 + l16;
                    const int byte = (m * (HDIM * 2) + (k32 * 32 + lk * 8) * 2) ^ ((m & 7) << 4);
                    a2[mi] = *(const bf16x8*)((const char*)hlds + byte);
                }
                bf16x8 bn2[4];
                if (k32 < 7) {
                    #pragma unroll
                    for (int ni = 0; ni < 4; ++ni)
                        bn2[ni] = *(const bf16x8*)(b2base[ni] + (size_t)(k32 + 1) * 512);
                }
                #pragma unroll
                for (int ni = 0; ni < 4; ++ni)
                    #pragma unroll
                    for (int mi = 0; mi < 4; ++mi)
                        acc2[mi][ni] = __builtin_amdgcn_mfma_f32_16x16x32_bf16(a2[mi], bc2[ni], acc2[mi][ni], 0, 0, 0);
                if (k32 < 7) {
                    #pragma unroll
                    for (int ni = 0; ni < 4; ++ni) bc2[ni] = bn2[ni];
                }
            }

            if (ATOMIC) {
                #pragma unroll
                for (int ni = 0; ni < 4; ++ni) {
                    const int n = jc * 256 + nq * 64 + ni * 16 + l16;
                    const float bv = b2[n];
                    #pragma unroll
                    for (int mi = 0; mi < 4; ++mi)
                        #pragma unroll
                        for (int r = 0; r < 4; ++r) {
                            const int m = mi * 16 + lk * 4 + r;
                            const float val = gelu_tanh(acc2[mi][ni][r] + bv) * tscs[mh * 64 + m];
                            atomicAdd(&y[(size_t)orow[mh * 64 + m] * DIM + n], val);
                        }
                }
            } else {
                ushort* os = ostage + w * (64 * OSW);
                #pragma unroll
                for (int p = 0; p < 2; ++p) {
                    asm volatile("s_waitcnt lgkmcnt(0)" ::: "memory");
                    #pragma unroll
                    for (int q = 0; q < 2; ++q) {
                        const int ni = p * 2 + q;
                        const float bv = b2[jc * 256 + nq * 64 + ni * 16 + l16];
                        #pragma unroll
                        for (int mi = 0; mi < 4; ++mi)
                            #pragma unroll
                            for (int r = 0; r < 4; ++r) {
                                const int m = mi * 16 + lk * 4 + r;
                                os[m * OSW + q * 16 + l16] = f2b(acc2[mi][ni][r] + bv);
                            }
                    }
                    asm volatile("s_waitcnt lgkmcnt(0)" ::: "memory");
                    #pragma unroll
                    for (int rr = 0; rr < 4; ++rr) {
                        const int m  = rr * 16 + (lane >> 2);
                        const int nl = (lane & 3) * 8;
                        u16x8 vv = *(const u16x8*)(os + m * OSW + nl);
                        *(u16x8*)(sbuf + (size_t)orow[mh * 64 + m] * DIM
                                  + jc * 256 + nq * 64 + p * 32 + nl) = vv;
                    }
                }
            }
        }
    }
}

// ---------------- gather: y = bf16(xn) + sum_s gelu(slot)*score ----------------
__global__ __launch_bounds__(256) void gather_kernel(
    const ushort* __restrict__ sbuf, const float* __restrict__ sscore,
    const ushort* __restrict__ xnb, float* __restrict__ y)
{
    const int idx = blockIdx.x * 256 + threadIdx.x;
    const int t = idx >> 8;
    const int d = (idx & 255) * 4;
    const ushort4 xr = *(const ushort4*)(xnb + (size_t)t * DIM + d);
    float4 a;
    a.x = b2f(xr.x); a.y = b2f(xr.y); a.z = b2f(xr.z); a.w = b2f(xr.w);
    #pragma unroll
    for (int s = 0; s < NSLOT; ++s) {
        const float sc = sscore[(size_t)t * NSLOT + s];
        const ushort4 u = *(const ushort4*)(sbuf + ((size_t)t * NSLOT + s) * DIM + d);
        a.x += gelu_tanh(b2f(u.x)) * sc;
        a.y += gelu_tanh(b2f(u.y)) * sc;
        a.z += gelu_tanh(b2f(u.z)) * sc;
        a.w += gelu_tanh(b2f(u.w)) * sc;
    }
    ((float4*)y)[idx] = a;
}

extern "C" void kernel_launch(void* const* d_in, const int* in_sizes, int n_in,
                              void* d_out, int out_size, void* d_ws, size_t ws_size,
                              hipStream_t stream) {
    const float* x      = (const float*)d_in[0];
    const float* rms_w  = (const float*)d_in[1];
    const float* cent   = (const float*)d_in[2];
    const float* sW1    = (const float*)d_in[3];
    const float* sb1    = (const float*)d_in[4];
    const float* sW2    = (const float*)d_in[5];
    const float* sb2    = (const float*)d_in[6];
    const float* rW1    = (const float*)d_in[7];
    const float* rb1    = (const float*)d_in[8];
    const float* rW2    = (const float*)d_in[9];
    const float* rb2    = (const float*)d_in[10];

    float* y_out   = (float*)d_out;
    float* aff_out = (float*)d_out + (size_t)T_TOK * DIM;

    char* p = (char*)d_ws;
    size_t off = 0;
    auto take = [&](size_t b) {
        char* r = p + off;
        off += (b + 255) & ~(size_t)255;
        return r;
    };
    ushort* xnb    = (ushort*)take((size_t)T_TOK * DIM * 2);
    ushort* W1p    = (ushort*)take((size_t)N_E * DIM * HDIM * 2);
    ushort* W2p    = (ushort*)take((size_t)N_E * HDIM * DIM * 2);
    int*    counts = (int*)take(N_RT * sizeof(int));
    int*    lists  = (int*)take((size_t)N_RT * T_TOK * 4);
    float*  sscore = (float*)take((size_t)T_TOK * NSLOT * 4);
    int*    tk_e   = (int*)take((size_t)T_TOK * TOPK * 4);
    ushort* sbuf   = (ushort*)take(((size_t)T_TOK * NSLOT + TB) * DIM * 2);
    const bool slot_ok = (off <= ws_size);

    pack_weights<<<dim3(64, N_E, 2), dim3(256), 0, stream>>>(
        sW1, rW1, sW2, rW2, W1p, W2p);

    rms_router_kernel<<<dim3(T_TOK / 8), dim3(256), 0, stream>>>(
        x, rms_w, cent, xnb, aff_out, tk_e, sscore);

    scatter_kernel<<<dim3(N_RT), dim3(256), 0, stream>>>(tk_e, counts, lists);

    const int grid = 64 + 8 * MAXPB;
    if (slot_ok) {
        moe_mfma<false><<<dim3(grid), dim3(512), 0, stream>>>(
            xnb, W1p, W2p, sb1, sb2, rb1, rb2, counts, lists,
            sscore, sbuf, y_out);
        gather_kernel<<<dim3((T_TOK * DIM / 4) / 256), dim3(256), 0, stream>>>(
            sbuf, sscore, xnb, y_out);
    } else {
        residual_init<<<dim3((T_TOK * DIM / 4) / 256), dim3(256), 0, stream>>>(
            xnb, y_out);
        moe_mfma<true><<<dim3(grid), dim3(512), 0, stream>>>(
            xnb, W1p, W2p, sb1, sb2, rb1, rb2, counts, lists,
            sscore, sbuf, y_out);
    }
}